// Round 9
// baseline (896.457 us; speedup 1.0000x reference)
//
#include <hip/hip_runtime.h>
#include <hip/hip_bf16.h>
#include <math.h>

#define NBATCH 16
#define NW 64
#define WA 49
#define NTOK (NBATCH*NW*WA)   // 50176
#define CCH 384
#define HIDDEN 1536

typedef __attribute__((ext_vector_type(8))) short short8;
typedef __attribute__((ext_vector_type(4))) float floatx4;

static __device__ __forceinline__ short f2bf(float f){
  unsigned u = __float_as_uint(f);
  unsigned r = (u + 0x7fff + ((u>>16)&1)) >> 16;
  return (short)r;
}
static __device__ __forceinline__ float bf2f(short s){
  return __uint_as_float(((unsigned)(unsigned short)s)<<16);
}

static __device__ __forceinline__ void gload16(const void* g, void* l){
  __builtin_amdgcn_global_load_lds(
      (const __attribute__((address_space(1))) void*)g,
      (__attribute__((address_space(3))) void*)l, 16, 0, 0);
}

// opaque LDS read: compiler cannot see the global_load_lds -> ds_read dependence,
// so it cannot insert a conservative s_waitcnt vmcnt(0). We own the waitcnts.
static __device__ __forceinline__ short8 ds_read_b128s(unsigned addr){
  short8 r;
  asm volatile("ds_read_b128 %0, %1" : "=v"(r) : "v"(addr));
  return r;
}

template<int N> __device__ __forceinline__ void waitvm();
template<> __device__ __forceinline__ void waitvm<0>(){ asm volatile("s_waitcnt vmcnt(0)" ::: "memory"); }
template<> __device__ __forceinline__ void waitvm<4>(){ asm volatile("s_waitcnt vmcnt(4)" ::: "memory"); }
template<> __device__ __forceinline__ void waitvm<6>(){ asm volatile("s_waitcnt vmcnt(6)" ::: "memory"); }

// token index -> pixel index (same map for LN1 gather and proj scatter)
static __device__ __forceinline__ int tok2pix(int t){
  int b = t / (NW*WA);
  int rem = t % (NW*WA);
  int w = rem / WA, a = rem % WA;
  int hs = (w>>3)*7 + a/7;
  int ws = (w&7)*7 + a%7;
  int hp = hs + 3; if (hp >= 56) hp -= 56;
  int wp = ws + 3; if (wp >= 56) wp -= 56;
  return (b*56 + hp)*56 + wp;
}

// ---- weight transpose + fp32->bf16 convert: W[K,N] -> Wt[N,K] ----
__global__ void wtconv(const float* __restrict__ W, short* __restrict__ Wt, int K, int N){
  int i = blockIdx.x*256 + threadIdx.x;
  if (i >= K*N) return;
  int k = i / N, n = i % N;
  Wt[(size_t)n*K + k] = f2bf(W[i]);
}

// ---- LayerNorm (one wave per token). MAP=1: gather via tok2pix (LN1+shift+window) ----
template<int MAP>
__global__ __launch_bounds__(256) void ln_kernel(const float* __restrict__ x,
    const float* __restrict__ g, const float* __restrict__ bta, short* __restrict__ out){
  int wid = threadIdx.x>>6, lane = threadIdx.x&63;
  int t = blockIdx.x*4 + wid;
  const float* row = x + (size_t)(MAP ? tok2pix(t) : t)*CCH;
  float v[6]; float s=0.f, ss=0.f;
  #pragma unroll
  for (int i=0;i<6;i++){ float f=row[lane+64*i]; v[i]=f; s+=f; ss+=f*f; }
  #pragma unroll
  for (int off=32; off; off>>=1){ s += __shfl_xor(s,off); ss += __shfl_xor(ss,off); }
  float mean = s*(1.f/384.f);
  float var  = ss*(1.f/384.f) - mean*mean;
  float inv  = rsqrtf(var + 1e-5f);
  short* orow = out + (size_t)t*CCH;
  #pragma unroll
  for (int i=0;i<6;i++){ int c=lane+64*i; orow[c] = f2bf((v[i]-mean)*inv*g[c]+bta[c]); }
}

// ---- 8-wave pipelined bf16 MFMA GEMM (R6 config: best measured).
// TRIPLE-buffered LDS, 2-step prefetch, one barrier + counted vmcnt per K-step.
// BM=128, BN=128, BK=64, waves 2M x 4N, wave tile 64 x 32.
// EPI 0: store bf16 (qkv)      EPI 1: proj -> y[pix] = x[pix] + v
template<int EPI, int KK, int BN>
__global__ __launch_bounds__(512) void gemm8(const short* __restrict__ A,
    const short* __restrict__ Bt, const float* __restrict__ bias,
    const float* __restrict__ res, void* __restrict__ outp,
    int N, int gx)
{
  constexpr int FN = BN/64;
  constexpr int NC = 2 + BN/64;
  __shared__ short As[3][128][64];
  __shared__ short Bs[3][BN][64];
  const int tid = threadIdx.x, lane = tid & 63, wid = tid >> 6;
  const int fr = lane & 15, fg = lane >> 4;
  const int wm = wid >> 2, wn = wid & 3;

  const int nwg = gridDim.x;
  const int q = nwg >> 3, r = nwg & 7;
  const int xcd = blockIdx.x & 7, pos = blockIdx.x >> 3;
  const int wgid = (xcd < r ? xcd*(q+1) : r*(q+1) + (xcd-r)*q) + pos;
  const int m0 = (wgid / gx) * 128, n0 = (wgid % gx) * BN;

  floatx4 acc[4][FN];
  #pragma unroll
  for (int m=0;m<4;m++)
    #pragma unroll
    for (int n=0;n<FN;n++) acc[m][n] = (floatx4){0.f,0.f,0.f,0.f};

  const int srow = tid >> 3;
  const int scol = ((tid & 7) ^ (srow & 7)) * 8;
  const short* gA = A  + (size_t)(m0 + srow) * KK + scol;
  const short* gB = Bt + (size_t)(n0 + srow) * KK + scol;
  constexpr int a64 = 64 * KK;
  short* aB = &As[0][wid*8][0];
  short* bB = &Bs[0][wid*8][0];
  constexpr int nt = KK >> 6;

  const unsigned aLds = (unsigned)(uintptr_t)&As[0][0][0];
  const unsigned bLds = (unsigned)(uintptr_t)&Bs[0][0][0];
  const unsigned rowOffA = (unsigned)((wm*64 + fr)*128);
  const unsigned rowOffB = (unsigned)((wn*(BN/4) + fr)*128);
  const unsigned pc0 = (unsigned)(((fg  ) ^ (fr&7))*16);
  const unsigned pc1 = (unsigned)(((4+fg) ^ (fr&7))*16);

#define STAGE(tt, bb) do{                                             \
    const int k0_ = (tt) << 6;                                        \
    short* a_ = aB + (bb)*128*64;                                     \
    short* b_ = bB + (bb)*BN*64;                                      \
    gload16(gA + k0_,        a_);                                     \
    gload16(gA + k0_ + a64,  a_ + 64*64);                             \
    _Pragma("unroll")                                                 \
    for (int c=0;c<FN;c++)                                            \
      gload16(gB + k0_ + (size_t)c*a64, b_ + c*64*64);                \
  }while(0)

  STAGE(0, 0);
  STAGE(1, 1);
  #pragma unroll
  for (int t = 0; t < nt; ++t){
    const int rb = t % 3;
    if (t + 1 < nt) waitvm<NC>();
    else            waitvm<0>();
    __builtin_amdgcn_s_barrier();
    if (t + 2 < nt) STAGE(t+2, (t+2)%3);
    const unsigned aoff = aLds + (unsigned)(rb*16384) + rowOffA;
    const unsigned boff = bLds + (unsigned)(rb*BN*128) + rowOffB;
    short8 a0[4], b0[FN], a1[4], b1[FN];
    #pragma unroll
    for (int m=0;m<4;m++) a0[m] = ds_read_b128s(aoff + (unsigned)(m*2048) + pc0);
    #pragma unroll
    for (int n=0;n<FN;n++) b0[n] = ds_read_b128s(boff + (unsigned)(n*2048) + pc0);
    #pragma unroll
    for (int m=0;m<4;m++) a1[m] = ds_read_b128s(aoff + (unsigned)(m*2048) + pc1);
    #pragma unroll
    for (int n=0;n<FN;n++) b1[n] = ds_read_b128s(boff + (unsigned)(n*2048) + pc1);
    if constexpr (FN==4) asm volatile("s_waitcnt lgkmcnt(8)" ::: "memory");
    else                 asm volatile("s_waitcnt lgkmcnt(6)" ::: "memory");
    __builtin_amdgcn_sched_barrier(0);
    __builtin_amdgcn_s_setprio(1);
    #pragma unroll
    for (int m=0;m<4;m++)
      #pragma unroll
      for (int n=0;n<FN;n++)
        acc[m][n] = __builtin_amdgcn_mfma_f32_16x16x32_bf16(a0[m], b0[n], acc[m][n], 0,0,0);
    __builtin_amdgcn_s_setprio(0);
    asm volatile("s_waitcnt lgkmcnt(0)" ::: "memory");
    __builtin_amdgcn_sched_barrier(0);
    __builtin_amdgcn_s_setprio(1);
    #pragma unroll
    for (int m=0;m<4;m++)
      #pragma unroll
      for (int n=0;n<FN;n++)
        acc[m][n] = __builtin_amdgcn_mfma_f32_16x16x32_bf16(a1[m], b1[n], acc[m][n], 0,0,0);
    __builtin_amdgcn_s_setprio(0);
  }
#undef STAGE

  #pragma unroll
  for (int n=0;n<FN;n++){
    int gc = n0 + wn*(BN/4) + n*16 + fr;
    float bv = bias[gc];
    #pragma unroll
    for (int m=0;m<4;m++){
      int gr0 = m0 + wm*64 + m*16 + fg*4;
      #pragma unroll
      for (int i=0;i<4;i++){
        int R = gr0 + i;
        float v = acc[m][n][i] + bv;
        if (EPI==0){
          ((short*)outp)[(size_t)R*N + gc] = f2bf(v);
        } else {
          int p = tok2pix(R); size_t idx=(size_t)p*CCH+gc;
          ((float*)outp)[idx] = res[idx] + v;
        }
      }
    }
  }
}

// ---- FUSED MLP: LN2 + fc1 + GELU + fc2 + residual, one block = 64 tokens.
// h (154MB) never touches HBM. Weights read directly from global (L2-hot).
// A-tile (LN output) and G-tile (gelu chunk) live in LDS, XOR-swizzled
// (we control both write and read sides; no global_load_lds constraint).
__global__ __launch_bounds__(512) void mlp_fused(
    const float* __restrict__ y,
    const float* __restrict__ g2v, const float* __restrict__ b2v,
    const short* __restrict__ W1,   // [1536][384] bf16
    const float* __restrict__ bias1,
    const short* __restrict__ W2,   // [384][1536] bf16
    const float* __restrict__ bias2,
    float* __restrict__ out)
{
  __shared__ short Al[64][384];   // 48 KB, slot-swizzled
  __shared__ short Gl[64][128];   // 16 KB, slot-swizzled
  const int tid = threadIdx.x, lane = tid & 63, wid = tid >> 6;
  const int fr = lane & 15, fg = lane >> 4;
  const int wm = wid >> 2, wn = wid & 3;
  const int t0 = blockIdx.x * 64;

  // ---- LN phase: wave w normalizes rows w*8..w*8+7; lane l<48 owns slot l ----
  float gw[8], bw[8];
  if (lane < 48){
    #pragma unroll
    for (int i=0;i<8;i++){ gw[i]=g2v[lane*8+i]; bw[i]=b2v[lane*8+i]; }
  }
  for (int j=0;j<8;j++){
    const int rr = wid*8 + j;
    const float* row = y + (size_t)(t0+rr)*384;
    float v[8]; float s=0.f, ss=0.f;
    if (lane < 48){
      float4 p0 = *(const float4*)&row[lane*8];
      float4 p1 = *(const float4*)&row[lane*8+4];
      v[0]=p0.x;v[1]=p0.y;v[2]=p0.z;v[3]=p0.w;
      v[4]=p1.x;v[5]=p1.y;v[6]=p1.z;v[7]=p1.w;
      #pragma unroll
      for (int i=0;i<8;i++){ s+=v[i]; ss+=v[i]*v[i]; }
    }
    #pragma unroll
    for (int off=32; off; off>>=1){ s += __shfl_xor(s,off); ss += __shfl_xor(ss,off); }
    float mean = s*(1.f/384.f);
    float var  = ss*(1.f/384.f) - mean*mean;
    float inv  = rsqrtf(var + 1e-5f);
    if (lane < 48){
      short8 o;
      #pragma unroll
      for (int i=0;i<8;i++) o[i] = f2bf((v[i]-mean)*inv*gw[i]+bw[i]);
      int ps = (lane & ~7) | ((lane&7) ^ (rr&7));
      *(short8*)&Al[rr][ps*8] = o;
    }
  }
  __syncthreads();

  floatx4 acc2[2][6];
  #pragma unroll
  for (int m=0;m<2;m++)
    #pragma unroll
    for (int n=0;n<6;n++) acc2[m][n] = (floatx4){0.f,0.f,0.f,0.f};

  const int arow0 = wm*32 + fr;        // A rows for m=0 (m=1: +16)
  for (int hc=0; hc<12; ++hc){
    // ---- stage1: acc1 = A(64x384) @ W1chunk^T -> 64x128 ----
    floatx4 acc1[2][2];
    #pragma unroll
    for (int m=0;m<2;m++)
      #pragma unroll
      for (int n=0;n<2;n++) acc1[m][n] = (floatx4){0.f,0.f,0.f,0.f};
    #pragma unroll
    for (int ks=0; ks<12; ++ks){
      short8 a[2], b[2];
      #pragma unroll
      for (int m=0;m<2;m++){
        int row = arow0 + m*16;
        int sl = ks*4 + fg;
        int ps = (sl & ~7) | ((sl&7) ^ (row&7));
        a[m] = *(const short8*)&Al[row][ps*8];
      }
      #pragma unroll
      for (int n=0;n<2;n++){
        int wr = hc*128 + wn*32 + n*16 + fr;
        b[n] = *(const short8*)&W1[(size_t)wr*384 + ks*32 + fg*8];
      }
      #pragma unroll
      for (int m=0;m<2;m++)
        #pragma unroll
        for (int n=0;n<2;n++)
          acc1[m][n] = __builtin_amdgcn_mfma_f32_16x16x32_bf16(a[m], b[n], acc1[m][n], 0,0,0);
    }
    // ---- GELU -> bf16 -> Gl (swizzled) ----
    #pragma unroll
    for (int n=0;n<2;n++){
      int gcol = wn*32 + n*16 + fr;
      float bv = bias1[hc*128 + gcol];
      int sl = gcol >> 3;
      #pragma unroll
      for (int m=0;m<2;m++){
        #pragma unroll
        for (int i=0;i<4;i++){
          int grow = wm*32 + m*16 + fg*4 + i;
          float vv = acc1[m][n][i] + bv;
          float u  = vv + 0.044715f*vv*vv*vv;
          float e  = __expf(1.5957691216057308f*u);
          float gg = 0.5f*vv*(2.f - 2.f/(e+1.f));
          int ps = (sl & 8) | ((sl&7) ^ (grow&7));
          Gl[grow][ps*8 + (fr&7)] = f2bf(gg);
        }
      }
    }
    __syncthreads();   // Gl visible to all waves
    // ---- stage2: acc2 += G(64x128) @ W2chunk^T -> 64x384 ----
    #pragma unroll
    for (int ks=0; ks<4; ++ks){
      short8 a[2], b[6];
      #pragma unroll
      for (int m=0;m<2;m++){
        int row = arow0 + m*16;
        int sl = ks*4 + fg;
        int ps = (sl & 8) | ((sl&7) ^ (row&7));
        a[m] = *(const short8*)&Gl[row][ps*8];
      }
      #pragma unroll
      for (int n=0;n<6;n++){
        int wr = wn*96 + n*16 + fr;
        b[n] = *(const short8*)&W2[(size_t)wr*1536 + hc*128 + ks*32 + fg*8];
      }
      #pragma unroll
      for (int m=0;m<2;m++)
        #pragma unroll
        for (int n=0;n<6;n++)
          acc2[m][n] = __builtin_amdgcn_mfma_f32_16x16x32_bf16(a[m], b[n], acc2[m][n], 0,0,0);
    }
    __syncthreads();   // all Gl reads done before next chunk rewrites
  }

  // ---- epilogue: out = y + fc2(out) + bias2 ----
  #pragma unroll
  for (int n=0;n<6;n++){
    int c = wn*96 + n*16 + fr;
    float bv = bias2[c];
    #pragma unroll
    for (int m=0;m<2;m++){
      #pragma unroll
      for (int i=0;i<4;i++){
        int row = t0 + wm*32 + m*16 + fg*4 + i;
        size_t idx = (size_t)row*384 + c;
        out[idx] = y[idx] + acc2[m][n][i] + bv;
      }
    }
  }
}

// ---- MFMA windowed attention: block = window, wave w -> heads w, w+4, w+8 ----
__global__ __launch_bounds__(256) void attn_mfma(const short* __restrict__ qkv,
    const float* __restrict__ rel_bias, short* __restrict__ attnout)
{
  __shared__ short Pl[4][64][68];
  __shared__ short Vt[4][32][68];
  __shared__ float lb[4][169];
  __shared__ int grp[64];
  const int wi = blockIdx.x;
  const int wid = threadIdx.x>>6, lane = threadIdx.x&63;
  const int fr = lane&15, fg = lane>>4;
  const int w = wi & 63, wh = w>>3, ww = w&7;
  if (threadIdx.x < 64){
    int t = threadIdx.x;
    int gv = 0;
    if (t < 49){
      int ai = t/7, aj = t%7;
      int hs = wh*7+ai, ws = ww*7+aj;
      int gh = hs<49?0:(hs<53?1:2);
      int gw = ws<49?0:(ws<53?1:2);
      gv = gh*3+gw;
    } else gv = -1;
    grp[t] = gv;
  }
  for (int t = lane; t < 32*15; t += 64){
    int d = t/15, j = 49 + t - d*15;
    Vt[wid][d][j] = 0;
  }
  __syncthreads();
  const size_t tbase = (size_t)wi*49;
  const float SCALE = 0.17677669529663687f;

  for (int hi=0; hi<3; ++hi){
    const int h = hi*4 + wid;
    for (int t = lane; t < 169; t += 64) lb[wid][t] = rel_bias[t*12 + h];
    for (int t = lane; t < 196; t += 64){
      int j = t>>2, d0 = (t&3)*8;
      short8 vv = *(const short8*)&qkv[(tbase+j)*1152 + 768 + h*32 + d0];
      #pragma unroll
      for (int s=0;s<8;s++) Vt[wid][d0+s][j] = vv[s];
    }
    short8 zf = {};
    short8 aq[4], bk[4];
    #pragma unroll
    for (int m=0;m<4;m++){
      int r = m*16+fr;
      aq[m] = (r<49) ? *(const short8*)&qkv[(tbase+r)*1152       + h*32 + fg*8] : zf;
      bk[m] = (r<49) ? *(const short8*)&qkv[(tbase+r)*1152 + 384 + h*32 + fg*8] : zf;
    }
    __syncthreads();   // (1) Vt/lb visible

    floatx4 sc[4][4];
    #pragma unroll
    for (int m=0;m<4;m++)
      #pragma unroll
      for (int n=0;n<4;n++)
        sc[m][n] = __builtin_amdgcn_mfma_f32_16x16x32_bf16(aq[m], bk[n], (floatx4){0.f,0.f,0.f,0.f}, 0,0,0);

    int ciC[4], cjC[4], gC[4], cvC[4];
    #pragma unroll
    for (int n=0;n<4;n++){
      int c = n*16+fr;
      ciC[n] = c/7; cjC[n] = c - ciC[n]*7;
      gC[n] = grp[c]; cvC[n] = (c<49);
    }
    #pragma unroll
    for (int m=0;m<4;m++){
      #pragma unroll
      for (int i=0;i<4;i++){
        int r = m*16 + fg*4 + i;
        int rv = (r<49);
        int ri = r/7, rj = r - ri*7;
        int gr = grp[r];
        float mxv = -3e30f;
        #pragma unroll
        for (int n=0;n<4;n++){
          float s;
          if (rv && cvC[n]){
            int dr = ri - ciC[n] + 6, dc = rj - cjC[n] + 6;
            s = sc[m][n][i]*SCALE + lb[wid][dr*13+dc];
            if (gr != gC[n]) s -= 100.f;
          } else s = -3e30f;
          sc[m][n][i] = s;
          mxv = fmaxf(mxv, s);
        }
        #pragma unroll
        for (int off=1;off<16;off<<=1) mxv = fmaxf(mxv, __shfl_xor(mxv, off));
        float sum = 0.f;
        #pragma unroll
        for (int n=0;n<4;n++){
          float e = __expf(sc[m][n][i]-mxv);
          sc[m][n][i] = e; sum += e;
        }
        #pragma unroll
        for (int off=1;off<16;off<<=1) sum += __shfl_xor(sum, off);
        float inv = 1.f/sum;
        #pragma unroll
        for (int n=0;n<4;n++)
          Pl[wid][r][n*16+fr] = f2bf(sc[m][n][i]*inv);
      }
    }
    __syncthreads();   // (2) P visible

    short8 pa[4][2], vb[2][2];
    #pragma unroll
    for (int m=0;m<4;m++)
      #pragma unroll
      for (int ks=0;ks<2;ks++)
        pa[m][ks] = *(const short8*)&Pl[wid][m*16+fr][ks*32+fg*8];
    #pragma unroll
    for (int n2=0;n2<2;n2++)
      #pragma unroll
      for (int ks=0;ks<2;ks++)
        vb[n2][ks] = *(const short8*)&Vt[wid][n2*16+fr][ks*32+fg*8];
    floatx4 oc[4][2];
    #pragma unroll
    for (int m=0;m<4;m++)
      #pragma unroll
      for (int n2=0;n2<2;n2++){
        oc[m][n2] = (floatx4){0.f,0.f,0.f,0.f};
        #pragma unroll
        for (int ks=0;ks<2;ks++)
          oc[m][n2] = __builtin_amdgcn_mfma_f32_16x16x32_bf16(pa[m][ks], vb[n2][ks], oc[m][n2], 0,0,0);
      }
    #pragma unroll
    for (int m=0;m<4;m++){
      #pragma unroll
      for (int i=0;i<4;i++){
        int r = m*16 + fg*4 + i;
        if (r < 49){
          #pragma unroll
          for (int n2=0;n2<2;n2++)
            attnout[(tbase+r)*384 + h*32 + n2*16 + fr] = f2bf(oc[m][n2][i]);
        }
      }
    }
    __syncthreads();   // (3) Vt reads done before next head's staging
  }
}

extern "C" void kernel_launch(void* const* d_in, const int* in_sizes, int n_in,
                              void* d_out, int out_size, void* d_ws, size_t ws_size,
                              hipStream_t stream)
{
  const float* x      = (const float*)d_in[0];
  const float* n1g    = (const float*)d_in[1];
  const float* n1b    = (const float*)d_in[2];
  const float* qkv_w  = (const float*)d_in[3];
  const float* qkv_b  = (const float*)d_in[4];
  const float* relb   = (const float*)d_in[5];
  const float* proj_w = (const float*)d_in[6];
  const float* proj_b = (const float*)d_in[7];
  const float* n2g    = (const float*)d_in[8];
  const float* n2b    = (const float*)d_in[9];
  const float* fc1_w  = (const float*)d_in[10];
  const float* fc1_b  = (const float*)d_in[11];
  const float* fc2_w  = (const float*)d_in[12];
  const float* fc2_b  = (const float*)d_in[13];

  char* ws = (char*)d_ws;
  const size_t SZ_XW  = (size_t)NTOK*CCH*2;
  const size_t SZ_QKV = (size_t)NTOK*1152*2;
  const size_t SZ_ATT = SZ_XW;
  const size_t SZ_Y   = (size_t)NTOK*CCH*4;

  short* xw    = (short*)(ws);
  short* qkvb  = (short*)(ws + SZ_XW);
  short* att   = (short*)(ws + SZ_XW + SZ_QKV);
  float* y     = (float*)(ws + SZ_XW + SZ_QKV + SZ_ATT);
  short* wbuf  = (short*)(ws + SZ_XW + SZ_QKV + SZ_ATT + SZ_Y);
  short* qkvWt = wbuf;                           // [1152][384]
  short* projWt= qkvWt + (size_t)1152*384;       // [384][384]
  short* fc1Wt = projWt + (size_t)384*384;       // [1536][384]
  short* fc2Wt = fc1Wt + (size_t)1536*384;       // [384][1536]

  wtconv<<<dim3((384*1152+255)/256), dim3(256), 0, stream>>>(qkv_w, qkvWt, 384, 1152);
  wtconv<<<dim3((384*384 +255)/256), dim3(256), 0, stream>>>(proj_w, projWt, 384, 384);
  wtconv<<<dim3((384*1536+255)/256), dim3(256), 0, stream>>>(fc1_w, fc1Wt, 384, 1536);
  wtconv<<<dim3((1536*384+255)/256), dim3(256), 0, stream>>>(fc2_w, fc2Wt, 1536, 384);

  ln_kernel<1><<<dim3(NTOK/4), dim3(256), 0, stream>>>(x, n1g, n1b, xw);
  gemm8<0,384,128><<<dim3(392*9), dim3(512), 0, stream>>>(xw,  qkvWt, qkv_b, nullptr, qkvb, 1152, 9);
  attn_mfma<<<dim3(NBATCH*NW), dim3(256), 0, stream>>>(qkvb, relb, att);
  gemm8<1,384,128><<<dim3(392*3), dim3(512), 0, stream>>>(att, projWt, proj_b, x, y, 384, 3);
  mlp_fused<<<dim3(NTOK/64), dim3(512), 0, stream>>>(y, n2g, n2b, fc1Wt, fc1_b, fc2Wt, fc2_b, (float*)d_out);
}

// Round 10
// 873.938 us; speedup vs baseline: 1.0258x; 1.0258x over previous
//
#include <hip/hip_runtime.h>
#include <hip/hip_bf16.h>
#include <math.h>

#define NBATCH 16
#define NW 64
#define WA 49
#define NTOK (NBATCH*NW*WA)   // 50176
#define CCH 384
#define HIDDEN 1536

typedef __attribute__((ext_vector_type(8))) short short8;
typedef __attribute__((ext_vector_type(4))) float floatx4;

static __device__ __forceinline__ short f2bf(float f){
  unsigned u = __float_as_uint(f);
  unsigned r = (u + 0x7fff + ((u>>16)&1)) >> 16;
  return (short)r;
}
static __device__ __forceinline__ float bf2f(short s){
  return __uint_as_float(((unsigned)(unsigned short)s)<<16);
}

// token index -> pixel index (same map for LN1 gather and proj scatter)
static __device__ __forceinline__ int tok2pix(int t){
  int b = t / (NW*WA);
  int rem = t % (NW*WA);
  int w = rem / WA, a = rem % WA;
  int hs = (w>>3)*7 + a/7;
  int ws = (w&7)*7 + a%7;
  int hp = hs + 3; if (hp >= 56) hp -= 56;
  int wp = ws + 3; if (wp >= 56) wp -= 56;
  return (b*56 + hp)*56 + wp;
}

// ---- weight transpose + fp32->bf16 convert: W[K,N] -> Wt[N,K] ----
__global__ void wtconv(const float* __restrict__ W, short* __restrict__ Wt, int K, int N){
  int i = blockIdx.x*256 + threadIdx.x;
  if (i >= K*N) return;
  int k = i / N, n = i % N;
  Wt[(size_t)n*K + k] = f2bf(W[i]);
}

// ---- LayerNorm (one wave per token). MAP=1: gather via tok2pix (LN1+shift+window) ----
template<int MAP>
__global__ __launch_bounds__(256) void ln_kernel(const float* __restrict__ x,
    const float* __restrict__ g, const float* __restrict__ bta, short* __restrict__ out){
  int wid = threadIdx.x>>6, lane = threadIdx.x&63;
  int t = blockIdx.x*4 + wid;
  const float* row = x + (size_t)(MAP ? tok2pix(t) : t)*CCH;
  float v[6]; float s=0.f, ss=0.f;
  #pragma unroll
  for (int i=0;i<6;i++){ float f=row[lane+64*i]; v[i]=f; s+=f; ss+=f*f; }
  #pragma unroll
  for (int off=32; off; off>>=1){ s += __shfl_xor(s,off); ss += __shfl_xor(ss,off); }
  float mean = s*(1.f/384.f);
  float var  = ss*(1.f/384.f) - mean*mean;
  float inv  = rsqrtf(var + 1e-5f);
  short* orow = out + (size_t)t*CCH;
  #pragma unroll
  for (int i=0;i<6;i++){ int c=lane+64*i; orow[c] = f2bf((v[i]-mean)*inv*g[c]+bta[c]); }
}

// ---- FLAT register-tiled bf16 MFMA GEMM (AITER flatmm style).
// NO LDS, NO barriers: each wave loads A/B fragments directly from global
// (64B-coalesced: 4 fg-lanes x 16B contiguous per row). B (<=1.2MB) is
// L2-resident; A-panel reuse across N-tiles via n-fastest XCD-grouped order.
// Wave tile 64x64 (acc 4x4), 4 waves/block stacked on M (block 256x64).
// Fully-unrolled K-loop, 2-deep register double-buffer, compiler-scheduled
// (no barriers -> loads float freely above MFMAs).
// C[M,N] = A[M,K]*Bt[N,K]^T + bias, fused epilogues:
// EPI 0: store bf16 (qkv)      EPI 1: proj -> y[pix] = x[pix] + v
// EPI 2: gelu -> bf16 (fc1)    EPI 3: out[t] = res[t] + v (fc2, fp32)
template<int EPI, int KK>
__global__ __launch_bounds__(256) void gemmR(const short* __restrict__ A,
    const short* __restrict__ Bt, const float* __restrict__ bias,
    const float* __restrict__ res, void* __restrict__ outp,
    int N, int gx)
{
  const int lane = threadIdx.x & 63, wid = threadIdx.x >> 6;
  const int fr = lane & 15, fg = lane >> 4;

  // bijective XCD swizzle (grids are all %8==0); wgid%gx = n-fastest so
  // consecutive wgid on one XCD share the same A row-panel (L2 reuse).
  const int nwg = gridDim.x;
  const int q = nwg >> 3, r = nwg & 7;
  const int xcd = blockIdx.x & 7, pos = blockIdx.x >> 3;
  const int wgid = (xcd < r ? xcd*(q+1) : r*(q+1) + (xcd-r)*q) + pos;
  const int m0 = (wgid / gx) * 256 + wid * 64;
  const int n0 = (wgid % gx) * 64;

  // fragment base pointers (per-lane): A rows m0+m*16+fr, B rows n0+n*16+fr,
  // k-offset fg*8; all k-steps become immediate offsets (<= 3072B < 4KB).
  const short* pa[4];
  const short* pb[4];
  #pragma unroll
  for (int m=0;m<4;m++) pa[m] = A  + (size_t)(m0 + m*16 + fr) * KK + fg*8;
  #pragma unroll
  for (int n=0;n<4;n++) pb[n] = Bt + (size_t)(n0 + n*16 + fr) * KK + fg*8;

  floatx4 acc[4][4];
  #pragma unroll
  for (int m=0;m<4;m++)
    #pragma unroll
    for (int n=0;n<4;n++) acc[m][n] = (floatx4){0.f,0.f,0.f,0.f};

  constexpr int nt = KK / 32;
  short8 a[2][4], b[2][4];

#define LOADF(j, kk_) do{                                              \
    _Pragma("unroll")                                                  \
    for (int m=0;m<4;m++) a[j][m] = *(const short8*)(pa[m] + (kk_));   \
    _Pragma("unroll")                                                  \
    for (int n=0;n<4;n++) b[j][n] = *(const short8*)(pb[n] + (kk_));   \
  }while(0)

  LOADF(0, 0);
  LOADF(1, 32);
  #pragma unroll
  for (int t = 0; t < nt; ++t){
    const int cur = t & 1;
    #pragma unroll
    for (int m=0;m<4;m++)
      #pragma unroll
      for (int n=0;n<4;n++)
        acc[m][n] = __builtin_amdgcn_mfma_f32_16x16x32_bf16(a[cur][m], b[cur][n], acc[m][n], 0,0,0);
    if (t + 2 < nt) LOADF(cur, (t+2)*32);
  }
#undef LOADF

  #pragma unroll
  for (int n=0;n<4;n++){
    int gc = n0 + n*16 + fr;
    float bv = bias[gc];
    #pragma unroll
    for (int m=0;m<4;m++){
      int gr0 = m0 + m*16 + fg*4;
      #pragma unroll
      for (int i=0;i<4;i++){
        int R = gr0 + i;
        float v = acc[m][n][i] + bv;
        if (EPI==0){
          ((short*)outp)[(size_t)R*N + gc] = f2bf(v);
        } else if (EPI==1){
          int p = tok2pix(R); size_t idx=(size_t)p*CCH+gc;
          ((float*)outp)[idx] = res[idx] + v;
        } else if (EPI==2){
          // tanh-approx GELU (max dev ~3e-4 vs erf form; threshold 0.11)
          float u  = v + 0.044715f*v*v*v;
          float e  = __expf(1.5957691216057308f*u);   // e^(2*0.79788456*u)
          float th = 1.f - 2.f/(e+1.f);
          float gg = 0.5f*v*(1.f+th);
          ((short*)outp)[(size_t)R*N+gc] = f2bf(gg);
        } else {
          size_t idx=(size_t)R*CCH+gc;
          ((float*)outp)[idx] = res[idx] + v;
        }
      }
    }
  }
}

// ---- MFMA windowed attention: block = window, wave w -> heads w, w+4, w+8 ----
__global__ __launch_bounds__(256) void attn_mfma(const short* __restrict__ qkv,
    const float* __restrict__ rel_bias, short* __restrict__ attnout)
{
  __shared__ short Pl[4][64][68];
  __shared__ short Vt[4][32][68];
  __shared__ float lb[4][169];
  __shared__ int grp[64];
  const int wi = blockIdx.x;
  const int wid = threadIdx.x>>6, lane = threadIdx.x&63;
  const int fr = lane&15, fg = lane>>4;
  const int w = wi & 63, wh = w>>3, ww = w&7;
  if (threadIdx.x < 64){
    int t = threadIdx.x;
    int gv = 0;
    if (t < 49){
      int ai = t/7, aj = t%7;
      int hs = wh*7+ai, ws = ww*7+aj;
      int gh = hs<49?0:(hs<53?1:2);
      int gw = ws<49?0:(ws<53?1:2);
      gv = gh*3+gw;
    } else gv = -1;
    grp[t] = gv;
  }
  for (int t = lane; t < 32*15; t += 64){
    int d = t/15, j = 49 + t - d*15;
    Vt[wid][d][j] = 0;
  }
  __syncthreads();
  const size_t tbase = (size_t)wi*49;
  const float SCALE = 0.17677669529663687f;

  for (int hi=0; hi<3; ++hi){
    const int h = hi*4 + wid;
    for (int t = lane; t < 169; t += 64) lb[wid][t] = rel_bias[t*12 + h];
    for (int t = lane; t < 196; t += 64){
      int j = t>>2, d0 = (t&3)*8;
      short8 vv = *(const short8*)&qkv[(tbase+j)*1152 + 768 + h*32 + d0];
      #pragma unroll
      for (int s=0;s<8;s++) Vt[wid][d0+s][j] = vv[s];
    }
    short8 zf = {};
    short8 aq[4], bk[4];
    #pragma unroll
    for (int m=0;m<4;m++){
      int r = m*16+fr;
      aq[m] = (r<49) ? *(const short8*)&qkv[(tbase+r)*1152       + h*32 + fg*8] : zf;
      bk[m] = (r<49) ? *(const short8*)&qkv[(tbase+r)*1152 + 384 + h*32 + fg*8] : zf;
    }
    __syncthreads();   // (1) Vt/lb visible

    floatx4 sc[4][4];
    #pragma unroll
    for (int m=0;m<4;m++)
      #pragma unroll
      for (int n=0;n<4;n++)
        sc[m][n] = __builtin_amdgcn_mfma_f32_16x16x32_bf16(aq[m], bk[n], (floatx4){0.f,0.f,0.f,0.f}, 0,0,0);

    int ciC[4], cjC[4], gC[4], cvC[4];
    #pragma unroll
    for (int n=0;n<4;n++){
      int c = n*16+fr;
      ciC[n] = c/7; cjC[n] = c - ciC[n]*7;
      gC[n] = grp[c]; cvC[n] = (c<49);
    }
    #pragma unroll
    for (int m=0;m<4;m++){
      #pragma unroll
      for (int i=0;i<4;i++){
        int r = m*16 + fg*4 + i;
        int rv = (r<49);
        int ri = r/7, rj = r - ri*7;
        int gr = grp[r];
        float mxv = -3e30f;
        #pragma unroll
        for (int n=0;n<4;n++){
          float s;
          if (rv && cvC[n]){
            int dr = ri - ciC[n] + 6, dc = rj - cjC[n] + 6;
            s = sc[m][n][i]*SCALE + lb[wid][dr*13+dc];
            if (gr != gC[n]) s -= 100.f;
          } else s = -3e30f;
          sc[m][n][i] = s;
          mxv = fmaxf(mxv, s);
        }
        #pragma unroll
        for (int off=1;off<16;off<<=1) mxv = fmaxf(mxv, __shfl_xor(mxv, off));
        float sum = 0.f;
        #pragma unroll
        for (int n=0;n<4;n++){
          float e = __expf(sc[m][n][i]-mxv);
          sc[m][n][i] = e; sum += e;
        }
        #pragma unroll
        for (int off=1;off<16;off<<=1) sum += __shfl_xor(sum, off);
        float inv = 1.f/sum;
        #pragma unroll
        for (int n=0;n<4;n++)
          Pl[wid][r][n*16+fr] = f2bf(sc[m][n][i]*inv);
      }
    }
    __syncthreads();   // (2) P visible

    short8 pa[4][2], vb[2][2];
    #pragma unroll
    for (int m=0;m<4;m++)
      #pragma unroll
      for (int ks=0;ks<2;ks++)
        pa[m][ks] = *(const short8*)&Pl[wid][m*16+fr][ks*32+fg*8];
    #pragma unroll
    for (int n2=0;n2<2;n2++)
      #pragma unroll
      for (int ks=0;ks<2;ks++)
        vb[n2][ks] = *(const short8*)&Vt[wid][n2*16+fr][ks*32+fg*8];
    floatx4 oc[4][2];
    #pragma unroll
    for (int m=0;m<4;m++)
      #pragma unroll
      for (int n2=0;n2<2;n2++){
        oc[m][n2] = (floatx4){0.f,0.f,0.f,0.f};
        #pragma unroll
        for (int ks=0;ks<2;ks++)
          oc[m][n2] = __builtin_amdgcn_mfma_f32_16x16x32_bf16(pa[m][ks], vb[n2][ks], oc[m][n2], 0,0,0);
      }
    #pragma unroll
    for (int m=0;m<4;m++){
      #pragma unroll
      for (int i=0;i<4;i++){
        int r = m*16 + fg*4 + i;
        if (r < 49){
          #pragma unroll
          for (int n2=0;n2<2;n2++)
            attnout[(tbase+r)*384 + h*32 + n2*16 + fr] = f2bf(oc[m][n2][i]);
        }
      }
    }
    __syncthreads();   // (3) Vt reads done before next head's staging
  }
}

extern "C" void kernel_launch(void* const* d_in, const int* in_sizes, int n_in,
                              void* d_out, int out_size, void* d_ws, size_t ws_size,
                              hipStream_t stream)
{
  const float* x      = (const float*)d_in[0];
  const float* n1g    = (const float*)d_in[1];
  const float* n1b    = (const float*)d_in[2];
  const float* qkv_w  = (const float*)d_in[3];
  const float* qkv_b  = (const float*)d_in[4];
  const float* relb   = (const float*)d_in[5];
  const float* proj_w = (const float*)d_in[6];
  const float* proj_b = (const float*)d_in[7];
  const float* n2g    = (const float*)d_in[8];
  const float* n2b    = (const float*)d_in[9];
  const float* fc1_w  = (const float*)d_in[10];
  const float* fc1_b  = (const float*)d_in[11];
  const float* fc2_w  = (const float*)d_in[12];
  const float* fc2_b  = (const float*)d_in[13];

  char* ws = (char*)d_ws;
  const size_t SZ_XW  = (size_t)NTOK*CCH*2;
  const size_t SZ_QKV = (size_t)NTOK*1152*2;
  const size_t SZ_ATT = SZ_XW;
  const size_t SZ_Y   = (size_t)NTOK*CCH*4;

  short* xw    = (short*)(ws);
  short* qkvb  = (short*)(ws + SZ_XW);
  short* att   = (short*)(ws + SZ_XW + SZ_QKV);
  float* y     = (float*)(ws + SZ_XW + SZ_QKV + SZ_ATT);
  short* wbuf  = (short*)(ws + SZ_XW + SZ_QKV + SZ_ATT + SZ_Y);
  short* qkvWt = wbuf;                           // [1152][384]
  short* projWt= qkvWt + (size_t)1152*384;       // [384][384]
  short* fc1Wt = projWt + (size_t)384*384;       // [1536][384]
  short* fc2Wt = fc1Wt + (size_t)1536*384;       // [384][1536]
  short* hbuf  = qkvb;                           // [NTOK][1536] (reuses qkv+att)
  short* hin   = xw;                             // [NTOK][384]  (reuses xw)

  wtconv<<<dim3((384*1152+255)/256), dim3(256), 0, stream>>>(qkv_w, qkvWt, 384, 1152);
  wtconv<<<dim3((384*384 +255)/256), dim3(256), 0, stream>>>(proj_w, projWt, 384, 384);
  wtconv<<<dim3((384*1536+255)/256), dim3(256), 0, stream>>>(fc1_w, fc1Wt, 384, 1536);
  wtconv<<<dim3((1536*384+255)/256), dim3(256), 0, stream>>>(fc2_w, fc2Wt, 1536, 384);

  ln_kernel<1><<<dim3(NTOK/4), dim3(256), 0, stream>>>(x, n1g, n1b, xw);
  gemmR<0,384><<<dim3(196*18),  dim3(256), 0, stream>>>(xw,  qkvWt, qkv_b, nullptr, qkvb, 1152, 18);
  attn_mfma<<<dim3(NBATCH*NW), dim3(256), 0, stream>>>(qkvb, relb, att);
  gemmR<1,384><<<dim3(196*6),   dim3(256), 0, stream>>>(att, projWt, proj_b, x, y, 384, 6);
  ln_kernel<0><<<dim3(NTOK/4), dim3(256), 0, stream>>>(y, n2g, n2b, hin);
  gemmR<2,384><<<dim3(196*24),  dim3(256), 0, stream>>>(hin, fc1Wt, fc1_b, nullptr, hbuf, 1536, 24);
  gemmR<3,1536><<<dim3(196*6),  dim3(256), 0, stream>>>(hbuf, fc2Wt, fc2_b, y, d_out, 384, 6);
}

// Round 11
// 646.470 us; speedup vs baseline: 1.3867x; 1.3519x over previous
//
#include <hip/hip_runtime.h>
#include <hip/hip_bf16.h>
#include <math.h>

#define NBATCH 16
#define NW 64
#define WA 49
#define NTOK (NBATCH*NW*WA)   // 50176
#define CCH 384
#define HIDDEN 1536

typedef __attribute__((ext_vector_type(8))) short short8;
typedef __attribute__((ext_vector_type(4))) float floatx4;

static __device__ __forceinline__ short f2bf(float f){
  unsigned u = __float_as_uint(f);
  unsigned r = (u + 0x7fff + ((u>>16)&1)) >> 16;
  return (short)r;
}
static __device__ __forceinline__ float bf2f(short s){
  return __uint_as_float(((unsigned)(unsigned short)s)<<16);
}

static __device__ __forceinline__ void gload16(const void* g, void* l){
  __builtin_amdgcn_global_load_lds(
      (const __attribute__((address_space(1))) void*)g,
      (__attribute__((address_space(3))) void*)l, 16, 0, 0);
}

// token index -> pixel index (same map for LN1 gather and proj scatter)
static __device__ __forceinline__ int tok2pix(int t){
  int b = t / (NW*WA);
  int rem = t % (NW*WA);
  int w = rem / WA, a = rem % WA;
  int hs = (w>>3)*7 + a/7;
  int ws = (w&7)*7 + a%7;
  int hp = hs + 3; if (hp >= 56) hp -= 56;
  int wp = ws + 3; if (wp >= 56) wp -= 56;
  return (b*56 + hp)*56 + wp;
}

// ---- weight transpose+convert into BLOCKED-SWIZZLED layout:
// Wt[panel p = n/64][slot s = k/8][row r = n%64, permuted r^=(s&7)][w = k%8]
// so a 48-slot chunk is 48KB CONTIGUOUS (linear gload16 staging) and
// ds_read_b128 of frag (slot, row) is bank-uniform.
__global__ void wtconvS(const float* __restrict__ W, short* __restrict__ Wt, int K, int N){
  int i = blockIdx.x*256 + threadIdx.x;
  if (i >= K*N) return;
  int k = i / N, n = i % N;
  int p = n>>6, r = n&63, s = k>>3, w = k&7;
  Wt[((size_t)p*(K>>3) + s)*512 + (((r ^ (s&7))<<3) | w)] = f2bf(W[i]);
}

// ---- LayerNorm (one wave per token). MAP=1: gather via tok2pix (LN1+shift+window) ----
template<int MAP>
__global__ __launch_bounds__(256) void ln_kernel(const float* __restrict__ x,
    const float* __restrict__ g, const float* __restrict__ bta, short* __restrict__ out){
  int wid = threadIdx.x>>6, lane = threadIdx.x&63;
  int t = blockIdx.x*4 + wid;
  const float* row = x + (size_t)(MAP ? tok2pix(t) : t)*CCH;
  float v[6]; float s=0.f, ss=0.f;
  #pragma unroll
  for (int i=0;i<6;i++){ float f=row[lane+64*i]; v[i]=f; s+=f; ss+=f*f; }
  #pragma unroll
  for (int off=32; off; off>>=1){ s += __shfl_xor(s,off); ss += __shfl_xor(ss,off); }
  float mean = s*(1.f/384.f);
  float var  = ss*(1.f/384.f) - mean*mean;
  float inv  = rsqrtf(var + 1e-5f);
  short* orow = out + (size_t)t*CCH;
  #pragma unroll
  for (int i=0;i<6;i++){ int c=lane+64*i; orow[c] = f2bf((v[i]-mean)*inv*g[c]+bta[c]); }
}

// ---- B-resident barrier-free bf16 MFMA GEMM.
// Block = 256 thr (4 waves stacked on M), tile 256x64. The ENTIRE B panel
// (64 x 384 = 48KB) is staged in LDS ONCE (per 48KB chunk for K=1536), then
// the K-loop runs with NO barriers: A-frags stream from global (plain loads,
// compiler-scheduled vmcnt), B-frags from LDS (plain ds_read, compiler
// lgkmcnt). 3 blocks/CU TLP + free software pipelining hide latency.
// C[M,N] = A[M,K]*B^T + bias; B in wtconvS blocked-swizzled layout.
// EPI 0: store bf16 (qkv)      EPI 1: proj -> y[pix] = x[pix] + v
// EPI 2: gelu -> bf16 (fc1)    EPI 3: out[t] = res[t] + v (fc2, fp32)
template<int EPI, int KK>
__global__ __launch_bounds__(256) void gemmS(const short* __restrict__ A,
    const short* __restrict__ Bt, const float* __restrict__ bias,
    const float* __restrict__ res, void* __restrict__ outp,
    int N, int gx)
{
  constexpr int NCH = KK/384;        // 48-slot chunks
  __shared__ short Bs[48*512];       // 48 KB
  const int tid = threadIdx.x, lane = tid & 63, wid = tid >> 6;
  const int fr = lane & 15, fg = lane >> 4;

  // bijective XCD swizzle; n-fastest so same-A-panel blocks share an XCD
  const int nwg = gridDim.x;
  const int q = nwg >> 3, r = nwg & 7;
  const int xcd = blockIdx.x & 7, pos = blockIdx.x >> 3;
  const int wgid = (xcd < r ? xcd*(q+1) : r*(q+1) + (xcd-r)*q) + pos;
  const int m0 = (wgid / gx) * 256 + wid * 64;
  const int n0 = (wgid % gx) * 64;

  // A fragment bases: row m0+m*16+fr, k-base fg*8 (k-step -> immediate offset)
  const short* pa[4];
  #pragma unroll
  for (int m=0;m<4;m++) pa[m] = A + (size_t)(m0 + m*16 + fr) * KK + fg*8;

  // B panel base (blocked layout: panel stride (KK/8)*512 shorts)
  const short* Bp = Bt + (size_t)(wgid % gx) * (KK>>3) * 512;

  // B read offsets: frag n, k-slot slv=t*4+fg lives at
  //   Bs[slv*512 + ((n*16+fr) ^ (slv&7))*8]; slv&7 = fg (t even) / 4+fg (t odd)
  int rs0[4], rs1[4];
  #pragma unroll
  for (int n=0;n<4;n++){
    rs0[n] = ((n*16+fr) ^ fg) * 8;
    rs1[n] = ((n*16+fr) ^ (4+fg)) * 8;
  }

  floatx4 acc[4][4];
  #pragma unroll
  for (int m=0;m<4;m++)
    #pragma unroll
    for (int n=0;n<4;n++) acc[m][n] = (floatx4){0.f,0.f,0.f,0.f};

  #pragma unroll
  for (int c=0; c<NCH; ++c){
    // ---- stage chunk c: 48KB contiguous, linear -> pre-swizzled layout ----
    if (c > 0) __syncthreads();      // all reads of previous chunk done
    {
      const short* src = Bp + (size_t)c*24576 + (size_t)tid*8;
      short* dst = &Bs[wid*512];     // wave-uniform; HW adds lane*16B
      #pragma unroll
      for (int j=0;j<12;j++)
        gload16(src + j*2048, dst + j*2048);
    }
    __syncthreads();                 // staging visible (compiler drains vmcnt)

    // ---- barrier-free K-loop: 12 steps of k=32 ----
    #pragma unroll
    for (int t=0; t<12; ++t){
      const int tt = c*12 + t;
      short8 a[4], b[4];
      #pragma unroll
      for (int m=0;m<4;m++) a[m] = *(const short8*)(pa[m] + tt*32);
      #pragma unroll
      for (int n=0;n<4;n++)
        b[n] = *(const short8*)&Bs[(t*4+fg)*512 + ((t&1) ? rs1[n] : rs0[n])];
      #pragma unroll
      for (int m=0;m<4;m++)
        #pragma unroll
        for (int n=0;n<4;n++)
          acc[m][n] = __builtin_amdgcn_mfma_f32_16x16x32_bf16(a[m], b[n], acc[m][n], 0,0,0);
    }
  }

  #pragma unroll
  for (int n=0;n<4;n++){
    int gc = n0 + n*16 + fr;
    float bv = bias[gc];
    #pragma unroll
    for (int m=0;m<4;m++){
      int gr0 = m0 + m*16 + fg*4;
      #pragma unroll
      for (int i=0;i<4;i++){
        int R = gr0 + i;
        float v = acc[m][n][i] + bv;
        if (EPI==0){
          ((short*)outp)[(size_t)R*N + gc] = f2bf(v);
        } else if (EPI==1){
          int p = tok2pix(R); size_t idx=(size_t)p*CCH+gc;
          ((float*)outp)[idx] = res[idx] + v;
        } else if (EPI==2){
          // tanh-approx GELU (max dev ~3e-4 vs erf form; threshold 0.11)
          float u  = v + 0.044715f*v*v*v;
          float e  = __expf(1.5957691216057308f*u);   // e^(2*0.79788456*u)
          float th = 1.f - 2.f/(e+1.f);
          float gg = 0.5f*v*(1.f+th);
          ((short*)outp)[(size_t)R*N+gc] = f2bf(gg);
        } else {
          size_t idx=(size_t)R*CCH+gc;
          ((float*)outp)[idx] = res[idx] + v;
        }
      }
    }
  }
}

// ---- MFMA windowed attention: block = window, wave w -> heads w, w+4, w+8 ----
__global__ __launch_bounds__(256) void attn_mfma(const short* __restrict__ qkv,
    const float* __restrict__ rel_bias, short* __restrict__ attnout)
{
  __shared__ short Pl[4][64][68];
  __shared__ short Vt[4][32][68];
  __shared__ float lb[4][169];
  __shared__ int grp[64];
  const int wi = blockIdx.x;
  const int wid = threadIdx.x>>6, lane = threadIdx.x&63;
  const int fr = lane&15, fg = lane>>4;
  const int w = wi & 63, wh = w>>3, ww = w&7;
  if (threadIdx.x < 64){
    int t = threadIdx.x;
    int gv = 0;
    if (t < 49){
      int ai = t/7, aj = t%7;
      int hs = wh*7+ai, ws = ww*7+aj;
      int gh = hs<49?0:(hs<53?1:2);
      int gw = ws<49?0:(ws<53?1:2);
      gv = gh*3+gw;
    } else gv = -1;
    grp[t] = gv;
  }
  for (int t = lane; t < 32*15; t += 64){
    int d = t/15, j = 49 + t - d*15;
    Vt[wid][d][j] = 0;
  }
  __syncthreads();
  const size_t tbase = (size_t)wi*49;
  const float SCALE = 0.17677669529663687f;

  for (int hi=0; hi<3; ++hi){
    const int h = hi*4 + wid;
    for (int t = lane; t < 169; t += 64) lb[wid][t] = rel_bias[t*12 + h];
    for (int t = lane; t < 196; t += 64){
      int j = t>>2, d0 = (t&3)*8;
      short8 vv = *(const short8*)&qkv[(tbase+j)*1152 + 768 + h*32 + d0];
      #pragma unroll
      for (int s=0;s<8;s++) Vt[wid][d0+s][j] = vv[s];
    }
    short8 zf = {};
    short8 aq[4], bk[4];
    #pragma unroll
    for (int m=0;m<4;m++){
      int r = m*16+fr;
      aq[m] = (r<49) ? *(const short8*)&qkv[(tbase+r)*1152       + h*32 + fg*8] : zf;
      bk[m] = (r<49) ? *(const short8*)&qkv[(tbase+r)*1152 + 384 + h*32 + fg*8] : zf;
    }
    __syncthreads();   // (1) Vt/lb visible

    floatx4 sc[4][4];
    #pragma unroll
    for (int m=0;m<4;m++)
      #pragma unroll
      for (int n=0;n<4;n++)
        sc[m][n] = __builtin_amdgcn_mfma_f32_16x16x32_bf16(aq[m], bk[n], (floatx4){0.f,0.f,0.f,0.f}, 0,0,0);

    int ciC[4], cjC[4], gC[4], cvC[4];
    #pragma unroll
    for (int n=0;n<4;n++){
      int c = n*16+fr;
      ciC[n] = c/7; cjC[n] = c - ciC[n]*7;
      gC[n] = grp[c]; cvC[n] = (c<49);
    }
    #pragma unroll
    for (int m=0;m<4;m++){
      #pragma unroll
      for (int i=0;i<4;i++){
        int r = m*16 + fg*4 + i;
        int rv = (r<49);
        int ri = r/7, rj = r - ri*7;
        int gr = grp[r];
        float mxv = -3e30f;
        #pragma unroll
        for (int n=0;n<4;n++){
          float s;
          if (rv && cvC[n]){
            int dr = ri - ciC[n] + 6, dc = rj - cjC[n] + 6;
            s = sc[m][n][i]*SCALE + lb[wid][dr*13+dc];
            if (gr != gC[n]) s -= 100.f;
          } else s = -3e30f;
          sc[m][n][i] = s;
          mxv = fmaxf(mxv, s);
        }
        #pragma unroll
        for (int off=1;off<16;off<<=1) mxv = fmaxf(mxv, __shfl_xor(mxv, off));
        float sum = 0.f;
        #pragma unroll
        for (int n=0;n<4;n++){
          float e = __expf(sc[m][n][i]-mxv);
          sc[m][n][i] = e; sum += e;
        }
        #pragma unroll
        for (int off=1;off<16;off<<=1) sum += __shfl_xor(sum, off);
        float inv = 1.f/sum;
        #pragma unroll
        for (int n=0;n<4;n++)
          Pl[wid][r][n*16+fr] = f2bf(sc[m][n][i]*inv);
      }
    }
    __syncthreads();   // (2) P visible

    short8 pa[4][2], vb[2][2];
    #pragma unroll
    for (int m=0;m<4;m++)
      #pragma unroll
      for (int ks=0;ks<2;ks++)
        pa[m][ks] = *(const short8*)&Pl[wid][m*16+fr][ks*32+fg*8];
    #pragma unroll
    for (int n2=0;n2<2;n2++)
      #pragma unroll
      for (int ks=0;ks<2;ks++)
        vb[n2][ks] = *(const short8*)&Vt[wid][n2*16+fr][ks*32+fg*8];
    floatx4 oc[4][2];
    #pragma unroll
    for (int m=0;m<4;m++)
      #pragma unroll
      for (int n2=0;n2<2;n2++){
        oc[m][n2] = (floatx4){0.f,0.f,0.f,0.f};
        #pragma unroll
        for (int ks=0;ks<2;ks++)
          oc[m][n2] = __builtin_amdgcn_mfma_f32_16x16x32_bf16(pa[m][ks], vb[n2][ks], oc[m][n2], 0,0,0);
      }
    #pragma unroll
    for (int m=0;m<4;m++){
      #pragma unroll
      for (int i=0;i<4;i++){
        int r = m*16 + fg*4 + i;
        if (r < 49){
          #pragma unroll
          for (int n2=0;n2<2;n2++)
            attnout[(tbase+r)*384 + h*32 + n2*16 + fr] = f2bf(oc[m][n2][i]);
        }
      }
    }
    __syncthreads();   // (3) Vt reads done before next head's staging
  }
}

extern "C" void kernel_launch(void* const* d_in, const int* in_sizes, int n_in,
                              void* d_out, int out_size, void* d_ws, size_t ws_size,
                              hipStream_t stream)
{
  const float* x      = (const float*)d_in[0];
  const float* n1g    = (const float*)d_in[1];
  const float* n1b    = (const float*)d_in[2];
  const float* qkv_w  = (const float*)d_in[3];
  const float* qkv_b  = (const float*)d_in[4];
  const float* relb   = (const float*)d_in[5];
  const float* proj_w = (const float*)d_in[6];
  const float* proj_b = (const float*)d_in[7];
  const float* n2g    = (const float*)d_in[8];
  const float* n2b    = (const float*)d_in[9];
  const float* fc1_w  = (const float*)d_in[10];
  const float* fc1_b  = (const float*)d_in[11];
  const float* fc2_w  = (const float*)d_in[12];
  const float* fc2_b  = (const float*)d_in[13];

  char* ws = (char*)d_ws;
  const size_t SZ_XW  = (size_t)NTOK*CCH*2;
  const size_t SZ_QKV = (size_t)NTOK*1152*2;
  const size_t SZ_ATT = SZ_XW;
  const size_t SZ_Y   = (size_t)NTOK*CCH*4;

  short* xw    = (short*)(ws);
  short* qkvb  = (short*)(ws + SZ_XW);
  short* att   = (short*)(ws + SZ_XW + SZ_QKV);
  float* y     = (float*)(ws + SZ_XW + SZ_QKV + SZ_ATT);
  short* wbuf  = (short*)(ws + SZ_XW + SZ_QKV + SZ_ATT + SZ_Y);
  short* qkvWt = wbuf;                           // blocked [18][48][64][8]
  short* projWt= qkvWt + (size_t)1152*384;       // blocked [6][48][64][8]
  short* fc1Wt = projWt + (size_t)384*384;       // blocked [24][48][64][8]
  short* fc2Wt = fc1Wt + (size_t)1536*384;       // blocked [6][192][64][8]
  short* hbuf  = qkvb;                           // [NTOK][1536] (reuses qkv+att)
  short* hin   = xw;                             // [NTOK][384]  (reuses xw)

  wtconvS<<<dim3((384*1152+255)/256), dim3(256), 0, stream>>>(qkv_w, qkvWt, 384, 1152);
  wtconvS<<<dim3((384*384 +255)/256), dim3(256), 0, stream>>>(proj_w, projWt, 384, 384);
  wtconvS<<<dim3((384*1536+255)/256), dim3(256), 0, stream>>>(fc1_w, fc1Wt, 384, 1536);
  wtconvS<<<dim3((1536*384+255)/256), dim3(256), 0, stream>>>(fc2_w, fc2Wt, 1536, 384);

  ln_kernel<1><<<dim3(NTOK/4), dim3(256), 0, stream>>>(x, n1g, n1b, xw);
  gemmS<0,384><<<dim3(196*18),  dim3(256), 0, stream>>>(xw,  qkvWt, qkv_b, nullptr, qkvb, 1152, 18);
  attn_mfma<<<dim3(NBATCH*NW), dim3(256), 0, stream>>>(qkvb, relb, att);
  gemmS<1,384><<<dim3(196*6),   dim3(256), 0, stream>>>(att, projWt, proj_b, x, y, 384, 6);
  ln_kernel<0><<<dim3(NTOK/4), dim3(256), 0, stream>>>(y, n2g, n2b, hin);
  gemmS<2,384><<<dim3(196*24),  dim3(256), 0, stream>>>(hin, fc1Wt, fc1_b, nullptr, hbuf, 1536, 24);
  gemmS<3,1536><<<dim3(196*6),  dim3(256), 0, stream>>>(hbuf, fc2Wt, fc2_b, y, d_out, 384, 6);
}

// Round 12
// 465.305 us; speedup vs baseline: 1.9266x; 1.3893x over previous
//
#include <hip/hip_runtime.h>
#include <hip/hip_bf16.h>
#include <math.h>

#define NBATCH 16
#define NW 64
#define WA 49
#define NTOK (NBATCH*NW*WA)   // 50176
#define CCH 384
#define HIDDEN 1536

typedef __attribute__((ext_vector_type(8))) short short8;
typedef __attribute__((ext_vector_type(4))) float floatx4;

static __device__ __forceinline__ short f2bf(float f){
  unsigned u = __float_as_uint(f);
  unsigned r = (u + 0x7fff + ((u>>16)&1)) >> 16;
  return (short)r;
}
static __device__ __forceinline__ float bf2f(short s){
  return __uint_as_float(((unsigned)(unsigned short)s)<<16);
}

static __device__ __forceinline__ void gload16(const void* g, void* l){
  __builtin_amdgcn_global_load_lds(
      (const __attribute__((address_space(1))) void*)g,
      (__attribute__((address_space(3))) void*)l, 16, 0, 0);
}

// opaque LDS read: compiler cannot see the global_load_lds -> ds_read dependence,
// so it cannot insert a conservative s_waitcnt vmcnt(0). We own the waitcnts.
static __device__ __forceinline__ short8 ds_read_b128s(unsigned addr){
  short8 r;
  asm volatile("ds_read_b128 %0, %1" : "=v"(r) : "v"(addr));
  return r;
}

template<int N> __device__ __forceinline__ void waitvm();
template<> __device__ __forceinline__ void waitvm<0>(){ asm volatile("s_waitcnt vmcnt(0)" ::: "memory"); }
template<> __device__ __forceinline__ void waitvm<5>(){ asm volatile("s_waitcnt vmcnt(5)" ::: "memory"); }

// token index -> pixel index (same map for LN1 gather and proj scatter)
static __device__ __forceinline__ int tok2pix(int t){
  int b = t / (NW*WA);
  int rem = t % (NW*WA);
  int w = rem / WA, a = rem % WA;
  int hs = (w>>3)*7 + a/7;
  int ws = (w&7)*7 + a%7;
  int hp = hs + 3; if (hp >= 56) hp -= 56;
  int wp = ws + 3; if (wp >= 56) wp -= 56;
  return (b*56 + hp)*56 + wp;
}

// ---- weight transpose + fp32->bf16 convert: W[K,N] -> Wt[N,K] ----
__global__ void wtconv(const float* __restrict__ W, short* __restrict__ Wt, int K, int N){
  int i = blockIdx.x*256 + threadIdx.x;
  if (i >= K*N) return;
  int k = i / N, n = i % N;
  Wt[(size_t)n*K + k] = f2bf(W[i]);
}

// ---- LayerNorm (one wave per token). MAP=1: gather via tok2pix (LN1+shift+window) ----
template<int MAP>
__global__ __launch_bounds__(256) void ln_kernel(const float* __restrict__ x,
    const float* __restrict__ g, const float* __restrict__ bta, short* __restrict__ out){
  int wid = threadIdx.x>>6, lane = threadIdx.x&63;
  int t = blockIdx.x*4 + wid;
  const float* row = x + (size_t)(MAP ? tok2pix(t) : t)*CCH;
  float v[6]; float s=0.f, ss=0.f;
  #pragma unroll
  for (int i=0;i<6;i++){ float f=row[lane+64*i]; v[i]=f; s+=f; ss+=f*f; }
  #pragma unroll
  for (int off=32; off; off>>=1){ s += __shfl_xor(s,off); ss += __shfl_xor(ss,off); }
  float mean = s*(1.f/384.f);
  float var  = ss*(1.f/384.f) - mean*mean;
  float inv  = rsqrtf(var + 1e-5f);
  short* orow = out + (size_t)t*CCH;
  #pragma unroll
  for (int i=0;i<6;i++){ int c=lane+64*i; orow[c] = f2bf((v[i]-mean)*inv*g[c]+bta[c]); }
}

// ---- 8-wave pipelined bf16 MFMA GEMM (R6 structure = measured best) with
// LDS-STAGED COALESCED EPILOGUE (fix: scalar C-writes were 32B-segment
// scattered -> 1.3 TB/s write BW; now short8/float4 row-major, 128-256B segs).
// BM=256, BN=64, BK=64, double-buffered, counted vmcnt(5), XOR-swizzled LDS.
// C[M,N] = A[M,K]*Bt[N,K]^T + bias, fused epilogues:
// EPI 0: store bf16 (qkv)      EPI 1: proj -> y[pix] = x[pix] + v
// EPI 2: gelu -> bf16 (fc1)    EPI 3: out[t] = res[t] + v (fc2, fp32)
template<int EPI, int KK>
__global__ __launch_bounds__(512) void gemm8(const short* __restrict__ A,
    const short* __restrict__ Bt, const float* __restrict__ bias,
    const float* __restrict__ res, void* __restrict__ outp,
    int N, int gx)
{
  __shared__ short As[2][256][64];   // 64 KB (reused as C-tile in epilogue)
  __shared__ short Bs[2][64][64];    // 16 KB
  const int tid = threadIdx.x, lane = tid & 63, wid = tid >> 6;
  const int fr = lane & 15, fg = lane >> 4;
  const int wm = wid >> 1, wn = wid & 1;

  // bijective XCD swizzle (m204); wgid%gx = n-block fastest -> consecutive wgid
  // on one XCD share the same A row-panel (A fetched once per XCD-L2).
  const int nwg = gridDim.x;
  const int q = nwg >> 3, r = nwg & 7;
  const int xcd = blockIdx.x & 7, pos = blockIdx.x >> 3;
  const int wgid = (xcd < r ? xcd*(q+1) : r*(q+1) + (xcd-r)*q) + pos;
  const int m0 = (wgid / gx) * 256, n0 = (wgid % gx) * 64;

  floatx4 acc[4][2];
  #pragma unroll
  for (int m=0;m<4;m++)
    #pragma unroll
    for (int n=0;n<2;n++) acc[m][n] = (floatx4){0.f,0.f,0.f,0.f};

  // staging: row = tid>>3 within a 64-row slab, physical slot = tid&7;
  // pre-swizzled GLOBAL column so read-side XOR sees logical data (rule #21)
  const int srow = tid >> 3;
  const int scol = ((tid & 7) ^ (srow & 7)) * 8;
  const short* gA = A  + (size_t)(m0 + srow) * KK + scol;
  const short* gB = Bt + (size_t)(n0 + srow) * KK + scol;
  constexpr int a64 = 64 * KK;
  short* aB = &As[0][wid*8][0];   // wave-uniform LDS bases (HW adds lane*16B)
  short* bB = &Bs[0][wid*8][0];
  constexpr int nt = KK >> 6;

  const unsigned aLds = (unsigned)(uintptr_t)&As[0][0][0];
  const unsigned bLds = (unsigned)(uintptr_t)&Bs[0][0][0];
  const unsigned rowOffA = (unsigned)((wm*64 + fr)*128);
  const unsigned rowOffB = (unsigned)((wn*32 + fr)*128);
  const unsigned pc0 = (unsigned)(((fg  ) ^ (fr&7))*16);
  const unsigned pc1 = (unsigned)(((4+fg) ^ (fr&7))*16);

#define STAGE(tt, bb) do{                                             \
    const int k0_ = (tt) << 6;                                        \
    short* a_ = aB + (bb)*256*64;                                     \
    short* b_ = bB + (bb)*64*64;                                      \
    gload16(gA + k0_,          a_);                                   \
    gload16(gA + k0_ +   a64,  a_ +  64*64);                          \
    gload16(gA + k0_ + 2*a64,  a_ + 128*64);                          \
    gload16(gA + k0_ + 3*a64,  a_ + 192*64);                          \
    gload16(gB + k0_,          b_);                                   \
  }while(0)

  STAGE(0, 0);
  #pragma unroll
  for (int t = 0; t < nt; ++t){
    const int buf = t & 1;
    if (t + 1 < nt){
      STAGE(t+1, buf^1);
      waitvm<5>();                     // stage t landed; t+1 in flight
    } else {
      waitvm<0>();
    }
    __builtin_amdgcn_s_barrier();      // all waves' stage-t writes visible
    const unsigned aoff = aLds + (unsigned)buf*32768u + rowOffA;
    const unsigned boff = bLds + (unsigned)buf*8192u  + rowOffB;
    #pragma unroll
    for (int kk=0; kk<2; ++kk){
      const unsigned pc = kk ? pc1 : pc0;
      short8 af[4], bq[2];
      #pragma unroll
      for (int m=0;m<4;m++) af[m] = ds_read_b128s(aoff + (unsigned)(m*2048) + pc);
      #pragma unroll
      for (int n=0;n<2;n++) bq[n] = ds_read_b128s(boff + (unsigned)(n*2048) + pc);
      asm volatile("s_waitcnt lgkmcnt(0)" ::: "memory");
      __builtin_amdgcn_sched_barrier(0);                 // rule #18
      __builtin_amdgcn_s_setprio(1);
      #pragma unroll
      for (int m=0;m<4;m++)
        #pragma unroll
        for (int n=0;n<2;n++)
          acc[m][n] = __builtin_amdgcn_mfma_f32_16x16x32_bf16(af[m], bq[n], acc[m][n], 0,0,0);
      __builtin_amdgcn_s_setprio(0);
    }
    __builtin_amdgcn_s_barrier();      // reads of buf done before it is re-staged
  }
#undef STAGE

  // ---- LDS-staged coalesced epilogue ----
  __syncthreads();                     // all ds_reads of As done before reuse
  if (EPI==0 || EPI==2){
    short* Cl = (short*)&As[0][0][0];  // [256][64] bf16 tile (32 KB)
    #pragma unroll
    for (int n=0;n<2;n++){
      int col = wn*32 + n*16 + fr;
      float bv = bias[n0 + col];
      #pragma unroll
      for (int m=0;m<4;m++){
        #pragma unroll
        for (int i=0;i<4;i++){
          int row = wm*64 + m*16 + fg*4 + i;
          float v = acc[m][n][i] + bv;
          if (EPI==2){
            // tanh-approx GELU (max dev ~3e-4 vs erf form; threshold 0.11)
            float u  = v + 0.044715f*v*v*v;
            float e  = __expf(1.5957691216057308f*u);
            v = 0.5f*v*(2.f - 2.f/(e+1.f));
          }
          Cl[row*64 + col] = f2bf(v);
        }
      }
    }
    __syncthreads();
    const int rr = tid >> 3, slot = tid & 7;
    #pragma unroll
    for (int it=0; it<4; ++it){
      int row = it*64 + rr;
      short8 v = *(const short8*)&Cl[row*64 + slot*8];
      *(short8*)&((short*)outp)[(size_t)(m0+row)*N + n0 + slot*8] = v;
    }
  } else {
    float* Cl = (float*)&As[0][0][0];  // [256][64] fp32 tile (64 KB)
    #pragma unroll
    for (int n=0;n<2;n++){
      int col = wn*32 + n*16 + fr;
      float bv = bias[n0 + col];
      #pragma unroll
      for (int m=0;m<4;m++){
        #pragma unroll
        for (int i=0;i<4;i++){
          int row = wm*64 + m*16 + fg*4 + i;
          Cl[row*64 + col] = acc[m][n][i] + bv;
        }
      }
    }
    __syncthreads();
    const int rr = tid >> 4, slot = tid & 15;
    #pragma unroll
    for (int it=0; it<8; ++it){
      int row = it*32 + rr;
      float4 v = *(const float4*)&Cl[row*64 + slot*4];
      size_t idx;
      if (EPI==1){
        int p = tok2pix(m0+row);
        idx = (size_t)p*CCH + n0 + slot*4;
      } else {
        idx = (size_t)(m0+row)*CCH + n0 + slot*4;
      }
      float4 rv = *(const float4*)&res[idx];
      v.x += rv.x; v.y += rv.y; v.z += rv.z; v.w += rv.w;
      *(float4*)&((float*)outp)[idx] = v;
    }
  }
}

// ---- MFMA windowed attention: block = window, wave w -> heads w, w+4, w+8 ----
__global__ __launch_bounds__(256) void attn_mfma(const short* __restrict__ qkv,
    const float* __restrict__ rel_bias, short* __restrict__ attnout)
{
  __shared__ short Pl[4][64][68];
  __shared__ short Vt[4][32][68];
  __shared__ float lb[4][169];
  __shared__ int grp[64];
  const int wi = blockIdx.x;
  const int wid = threadIdx.x>>6, lane = threadIdx.x&63;
  const int fr = lane&15, fg = lane>>4;
  const int w = wi & 63, wh = w>>3, ww = w&7;
  if (threadIdx.x < 64){
    int t = threadIdx.x;
    int gv = 0;
    if (t < 49){
      int ai = t/7, aj = t%7;
      int hs = wh*7+ai, ws = ww*7+aj;
      int gh = hs<49?0:(hs<53?1:2);
      int gw = ws<49?0:(ws<53?1:2);
      gv = gh*3+gw;
    } else gv = -1;
    grp[t] = gv;
  }
  for (int t = lane; t < 32*15; t += 64){
    int d = t/15, j = 49 + t - d*15;
    Vt[wid][d][j] = 0;
  }
  __syncthreads();
  const size_t tbase = (size_t)wi*49;
  const float SCALE = 0.17677669529663687f;

  for (int hi=0; hi<3; ++hi){
    const int h = hi*4 + wid;
    for (int t = lane; t < 169; t += 64) lb[wid][t] = rel_bias[t*12 + h];
    for (int t = lane; t < 196; t += 64){
      int j = t>>2, d0 = (t&3)*8;
      short8 vv = *(const short8*)&qkv[(tbase+j)*1152 + 768 + h*32 + d0];
      #pragma unroll
      for (int s=0;s<8;s++) Vt[wid][d0+s][j] = vv[s];
    }
    short8 zf = {};
    short8 aq[4], bk[4];
    #pragma unroll
    for (int m=0;m<4;m++){
      int r = m*16+fr;
      aq[m] = (r<49) ? *(const short8*)&qkv[(tbase+r)*1152       + h*32 + fg*8] : zf;
      bk[m] = (r<49) ? *(const short8*)&qkv[(tbase+r)*1152 + 384 + h*32 + fg*8] : zf;
    }
    __syncthreads();   // (1) Vt/lb visible

    floatx4 sc[4][4];
    #pragma unroll
    for (int m=0;m<4;m++)
      #pragma unroll
      for (int n=0;n<4;n++)
        sc[m][n] = __builtin_amdgcn_mfma_f32_16x16x32_bf16(aq[m], bk[n], (floatx4){0.f,0.f,0.f,0.f}, 0,0,0);

    int ciC[4], cjC[4], gC[4], cvC[4];
    #pragma unroll
    for (int n=0;n<4;n++){
      int c = n*16+fr;
      ciC[n] = c/7; cjC[n] = c - ciC[n]*7;
      gC[n] = grp[c]; cvC[n] = (c<49);
    }
    #pragma unroll
    for (int m=0;m<4;m++){
      #pragma unroll
      for (int i=0;i<4;i++){
        int r = m*16 + fg*4 + i;
        int rv = (r<49);
        int ri = r/7, rj = r - ri*7;
        int gr = grp[r];
        float mxv = -3e30f;
        #pragma unroll
        for (int n=0;n<4;n++){
          float s;
          if (rv && cvC[n]){
            int dr = ri - ciC[n] + 6, dc = rj - cjC[n] + 6;
            s = sc[m][n][i]*SCALE + lb[wid][dr*13+dc];
            if (gr != gC[n]) s -= 100.f;
          } else s = -3e30f;
          sc[m][n][i] = s;
          mxv = fmaxf(mxv, s);
        }
        #pragma unroll
        for (int off=1;off<16;off<<=1) mxv = fmaxf(mxv, __shfl_xor(mxv, off));
        float sum = 0.f;
        #pragma unroll
        for (int n=0;n<4;n++){
          float e = __expf(sc[m][n][i]-mxv);
          sc[m][n][i] = e; sum += e;
        }
        #pragma unroll
        for (int off=1;off<16;off<<=1) sum += __shfl_xor(sum, off);
        float inv = 1.f/sum;
        #pragma unroll
        for (int n=0;n<4;n++)
          Pl[wid][r][n*16+fr] = f2bf(sc[m][n][i]*inv);
      }
    }
    __syncthreads();   // (2) P visible

    short8 pa[4][2], vb[2][2];
    #pragma unroll
    for (int m=0;m<4;m++)
      #pragma unroll
      for (int ks=0;ks<2;ks++)
        pa[m][ks] = *(const short8*)&Pl[wid][m*16+fr][ks*32+fg*8];
    #pragma unroll
    for (int n2=0;n2<2;n2++)
      #pragma unroll
      for (int ks=0;ks<2;ks++)
        vb[n2][ks] = *(const short8*)&Vt[wid][n2*16+fr][ks*32+fg*8];
    floatx4 oc[4][2];
    #pragma unroll
    for (int m=0;m<4;m++)
      #pragma unroll
      for (int n2=0;n2<2;n2++){
        oc[m][n2] = (floatx4){0.f,0.f,0.f,0.f};
        #pragma unroll
        for (int ks=0;ks<2;ks++)
          oc[m][n2] = __builtin_amdgcn_mfma_f32_16x16x32_bf16(pa[m][ks], vb[n2][ks], oc[m][n2], 0,0,0);
      }
    #pragma unroll
    for (int m=0;m<4;m++){
      #pragma unroll
      for (int i=0;i<4;i++){
        int r = m*16 + fg*4 + i;
        if (r < 49){
          #pragma unroll
          for (int n2=0;n2<2;n2++)
            attnout[(tbase+r)*384 + h*32 + n2*16 + fr] = f2bf(oc[m][n2][i]);
        }
      }
    }
    __syncthreads();   // (3) Vt reads done before next head's staging
  }
}

extern "C" void kernel_launch(void* const* d_in, const int* in_sizes, int n_in,
                              void* d_out, int out_size, void* d_ws, size_t ws_size,
                              hipStream_t stream)
{
  const float* x      = (const float*)d_in[0];
  const float* n1g    = (const float*)d_in[1];
  const float* n1b    = (const float*)d_in[2];
  const float* qkv_w  = (const float*)d_in[3];
  const float* qkv_b  = (const float*)d_in[4];
  const float* relb   = (const float*)d_in[5];
  const float* proj_w = (const float*)d_in[6];
  const float* proj_b = (const float*)d_in[7];
  const float* n2g    = (const float*)d_in[8];
  const float* n2b    = (const float*)d_in[9];
  const float* fc1_w  = (const float*)d_in[10];
  const float* fc1_b  = (const float*)d_in[11];
  const float* fc2_w  = (const float*)d_in[12];
  const float* fc2_b  = (const float*)d_in[13];

  char* ws = (char*)d_ws;
  const size_t SZ_XW  = (size_t)NTOK*CCH*2;
  const size_t SZ_QKV = (size_t)NTOK*1152*2;
  const size_t SZ_ATT = SZ_XW;
  const size_t SZ_Y   = (size_t)NTOK*CCH*4;

  short* xw    = (short*)(ws);
  short* qkvb  = (short*)(ws + SZ_XW);
  short* att   = (short*)(ws + SZ_XW + SZ_QKV);
  float* y     = (float*)(ws + SZ_XW + SZ_QKV + SZ_ATT);
  short* wbuf  = (short*)(ws + SZ_XW + SZ_QKV + SZ_ATT + SZ_Y);
  short* qkvWt = wbuf;                           // [1152][384]
  short* projWt= qkvWt + (size_t)1152*384;       // [384][384]
  short* fc1Wt = projWt + (size_t)384*384;       // [1536][384]
  short* fc2Wt = fc1Wt + (size_t)1536*384;       // [384][1536]
  short* hbuf  = qkvb;                           // [NTOK][1536] (reuses qkv+att)
  short* hin   = xw;                             // [NTOK][384]  (reuses xw)

  wtconv<<<dim3((384*1152+255)/256), dim3(256), 0, stream>>>(qkv_w, qkvWt, 384, 1152);
  wtconv<<<dim3((384*384 +255)/256), dim3(256), 0, stream>>>(proj_w, projWt, 384, 384);
  wtconv<<<dim3((384*1536+255)/256), dim3(256), 0, stream>>>(fc1_w, fc1Wt, 384, 1536);
  wtconv<<<dim3((1536*384+255)/256), dim3(256), 0, stream>>>(fc2_w, fc2Wt, 1536, 384);

  ln_kernel<1><<<dim3(NTOK/4), dim3(256), 0, stream>>>(x, n1g, n1b, xw);
  gemm8<0,384><<<dim3(18*196), dim3(512), 0, stream>>>(xw,  qkvWt, qkv_b, nullptr, qkvb, 1152, 18);
  attn_mfma<<<dim3(NBATCH*NW), dim3(256), 0, stream>>>(qkvb, relb, att);
  gemm8<1,384><<<dim3(6*196),  dim3(512), 0, stream>>>(att, projWt, proj_b, x, y, 384, 6);
  ln_kernel<0><<<dim3(NTOK/4), dim3(256), 0, stream>>>(y, n2g, n2b, hin);
  gemm8<2,384><<<dim3(24*196), dim3(512), 0, stream>>>(hin, fc1Wt, fc1_b, nullptr, hbuf, 1536, 24);
  gemm8<3,1536><<<dim3(6*196), dim3(512), 0, stream>>>(hbuf, fc2Wt, fc2_b, y, d_out, 384, 6);
}

// Round 13
// 401.415 us; speedup vs baseline: 2.2332x; 1.1592x over previous
//
#include <hip/hip_runtime.h>
#include <hip/hip_bf16.h>
#include <math.h>

#define NBATCH 16
#define NW 64
#define WA 49
#define NTOK (NBATCH*NW*WA)   // 50176
#define CCH 384
#define HIDDEN 1536

typedef __attribute__((ext_vector_type(8))) short short8;
typedef __attribute__((ext_vector_type(4))) float floatx4;

static __device__ __forceinline__ short f2bf(float f){
  unsigned u = __float_as_uint(f);
  unsigned r = (u + 0x7fff + ((u>>16)&1)) >> 16;
  return (short)r;
}
static __device__ __forceinline__ float bf2f(short s){
  return __uint_as_float(((unsigned)(unsigned short)s)<<16);
}

static __device__ __forceinline__ void gload16(const void* g, void* l){
  __builtin_amdgcn_global_load_lds(
      (const __attribute__((address_space(1))) void*)g,
      (__attribute__((address_space(3))) void*)l, 16, 0, 0);
}

// opaque LDS reads: compiler cannot see global_load_lds -> ds_read dependence;
// we own the waitcnts (rule #18: lgkmcnt + sched_barrier before MFMA).
static __device__ __forceinline__ short8 ds_read_b128s(unsigned addr){
  short8 r;
  asm volatile("ds_read_b128 %0, %1" : "=v"(r) : "v"(addr));
  return r;
}
static __device__ __forceinline__ long ds_read_b64s(unsigned addr){
  long r;
  asm volatile("ds_read_b64 %0, %1" : "=v"(r) : "v"(addr));
  return r;
}

template<int N> __device__ __forceinline__ void waitvm();
template<> __device__ __forceinline__ void waitvm<0>(){ asm volatile("s_waitcnt vmcnt(0)" ::: "memory"); }
template<> __device__ __forceinline__ void waitvm<5>(){ asm volatile("s_waitcnt vmcnt(5)" ::: "memory"); }

// token index -> pixel index (same map for LN1 gather and proj scatter)
static __device__ __forceinline__ int tok2pix(int t){
  int b = t / (NW*WA);
  int rem = t % (NW*WA);
  int w = rem / WA, a = rem % WA;
  int hs = (w>>3)*7 + a/7;
  int ws = (w&7)*7 + a%7;
  int hp = hs + 3; if (hp >= 56) hp -= 56;
  int wp = ws + 3; if (wp >= 56) wp -= 56;
  return (b*56 + hp)*56 + wp;
}

// ---- weight transpose + fp32->bf16 convert: W[K,N] -> Wt[N,K] ----
__global__ void wtconv(const float* __restrict__ W, short* __restrict__ Wt, int K, int N){
  int i = blockIdx.x*256 + threadIdx.x;
  if (i >= K*N) return;
  int k = i / N, n = i % N;
  Wt[(size_t)n*K + k] = f2bf(W[i]);
}

// ---- weight transpose + fp32->fp8(e4m3) convert: W[K,N] -> Wt8[N,K] ----
__global__ void wtconv8(const float* __restrict__ W, unsigned char* __restrict__ Wt, int K, int N){
  int i = blockIdx.x*256 + threadIdx.x;
  if (i >= K*N) return;
  int k = i / N, n = i % N;
  unsigned pk = (unsigned)__builtin_amdgcn_cvt_pk_fp8_f32(W[i], W[i], 0, false);
  Wt[(size_t)n*K + k] = (unsigned char)(pk & 0xff);
}

// ---- LayerNorm (one wave per token). MAP=1: gather via tok2pix (LN1+shift+window) ----
template<int MAP>
__global__ __launch_bounds__(256) void ln_kernel(const float* __restrict__ x,
    const float* __restrict__ g, const float* __restrict__ bta, short* __restrict__ out){
  int wid = threadIdx.x>>6, lane = threadIdx.x&63;
  int t = blockIdx.x*4 + wid;
  const float* row = x + (size_t)(MAP ? tok2pix(t) : t)*CCH;
  float v[6]; float s=0.f, ss=0.f;
  #pragma unroll
  for (int i=0;i<6;i++){ float f=row[lane+64*i]; v[i]=f; s+=f; ss+=f*f; }
  #pragma unroll
  for (int off=32; off; off>>=1){ s += __shfl_xor(s,off); ss += __shfl_xor(ss,off); }
  float mean = s*(1.f/384.f);
  float var  = ss*(1.f/384.f) - mean*mean;
  float inv  = rsqrtf(var + 1e-5f);
  short* orow = out + (size_t)t*CCH;
  #pragma unroll
  for (int i=0;i<6;i++){ int c=lane+64*i; orow[c] = f2bf((v[i]-mean)*inv*g[c]+bta[c]); }
}

// ---- 8-wave pipelined bf16 MFMA GEMM (R12 structure) w/ coalesced epilogue.
// BM=256, BN=64, BK=64, double-buffered, counted vmcnt(5), XOR-swizzled LDS.
// EPI 0: store bf16 (qkv)   EPI 1: proj -> y[pix] = x[pix] + v
// EPI 2: sigmoid-GELU -> fp8 e4m3 (fc1; outp is byte array, N in bytes)
template<int EPI, int KK>
__global__ __launch_bounds__(512) void gemm8(const short* __restrict__ A,
    const short* __restrict__ Bt, const float* __restrict__ bias,
    const float* __restrict__ res, void* __restrict__ outp,
    int N, int gx)
{
  __shared__ short As[2][256][64];   // 64 KB (reused as C-tile in epilogue)
  __shared__ short Bs[2][64][64];    // 16 KB
  const int tid = threadIdx.x, lane = tid & 63, wid = tid >> 6;
  const int fr = lane & 15, fg = lane >> 4;
  const int wm = wid >> 1, wn = wid & 1;

  const int nwg = gridDim.x;
  const int q = nwg >> 3, r = nwg & 7;
  const int xcd = blockIdx.x & 7, pos = blockIdx.x >> 3;
  const int wgid = (xcd < r ? xcd*(q+1) : r*(q+1) + (xcd-r)*q) + pos;
  const int m0 = (wgid / gx) * 256, n0 = (wgid % gx) * 64;

  floatx4 acc[4][2];
  #pragma unroll
  for (int m=0;m<4;m++)
    #pragma unroll
    for (int n=0;n<2;n++) acc[m][n] = (floatx4){0.f,0.f,0.f,0.f};

  const int srow = tid >> 3;
  const int scol = ((tid & 7) ^ (srow & 7)) * 8;
  const short* gA = A  + (size_t)(m0 + srow) * KK + scol;
  const short* gB = Bt + (size_t)(n0 + srow) * KK + scol;
  constexpr int a64 = 64 * KK;
  short* aB = &As[0][wid*8][0];
  short* bB = &Bs[0][wid*8][0];
  constexpr int nt = KK >> 6;

  const unsigned aLds = (unsigned)(uintptr_t)&As[0][0][0];
  const unsigned bLds = (unsigned)(uintptr_t)&Bs[0][0][0];
  const unsigned rowOffA = (unsigned)((wm*64 + fr)*128);
  const unsigned rowOffB = (unsigned)((wn*32 + fr)*128);
  const unsigned pc0 = (unsigned)(((fg  ) ^ (fr&7))*16);
  const unsigned pc1 = (unsigned)(((4+fg) ^ (fr&7))*16);

#define STAGE(tt, bb) do{                                             \
    const int k0_ = (tt) << 6;                                        \
    short* a_ = aB + (bb)*256*64;                                     \
    short* b_ = bB + (bb)*64*64;                                      \
    gload16(gA + k0_,          a_);                                   \
    gload16(gA + k0_ +   a64,  a_ +  64*64);                          \
    gload16(gA + k0_ + 2*a64,  a_ + 128*64);                          \
    gload16(gA + k0_ + 3*a64,  a_ + 192*64);                          \
    gload16(gB + k0_,          b_);                                   \
  }while(0)

  STAGE(0, 0);
  #pragma unroll
  for (int t = 0; t < nt; ++t){
    const int buf = t & 1;
    if (t + 1 < nt){
      STAGE(t+1, buf^1);
      waitvm<5>();
    } else {
      waitvm<0>();
    }
    __builtin_amdgcn_s_barrier();
    const unsigned aoff = aLds + (unsigned)buf*32768u + rowOffA;
    const unsigned boff = bLds + (unsigned)buf*8192u  + rowOffB;
    #pragma unroll
    for (int kk=0; kk<2; ++kk){
      const unsigned pc = kk ? pc1 : pc0;
      short8 af[4], bq[2];
      #pragma unroll
      for (int m=0;m<4;m++) af[m] = ds_read_b128s(aoff + (unsigned)(m*2048) + pc);
      #pragma unroll
      for (int n=0;n<2;n++) bq[n] = ds_read_b128s(boff + (unsigned)(n*2048) + pc);
      asm volatile("s_waitcnt lgkmcnt(0)" ::: "memory");
      __builtin_amdgcn_sched_barrier(0);
      __builtin_amdgcn_s_setprio(1);
      #pragma unroll
      for (int m=0;m<4;m++)
        #pragma unroll
        for (int n=0;n<2;n++)
          acc[m][n] = __builtin_amdgcn_mfma_f32_16x16x32_bf16(af[m], bq[n], acc[m][n], 0,0,0);
      __builtin_amdgcn_s_setprio(0);
    }
    __builtin_amdgcn_s_barrier();
  }
#undef STAGE

  // ---- LDS-staged coalesced epilogue ----
  __syncthreads();
  if (EPI==0){
    short* Cl = (short*)&As[0][0][0];  // [256][64] bf16
    #pragma unroll
    for (int n=0;n<2;n++){
      int col = wn*32 + n*16 + fr;
      float bv = bias[n0 + col];
      #pragma unroll
      for (int m=0;m<4;m++){
        #pragma unroll
        for (int i=0;i<4;i++){
          int row = wm*64 + m*16 + fg*4 + i;
          Cl[row*64 + col] = f2bf(acc[m][n][i] + bv);
        }
      }
    }
    __syncthreads();
    const int rr = tid >> 3, slot = tid & 7;
    #pragma unroll
    for (int it=0; it<4; ++it){
      int row = it*64 + rr;
      short8 v = *(const short8*)&Cl[row*64 + slot*8];
      *(short8*)&((short*)outp)[(size_t)(m0+row)*N + n0 + slot*8] = v;
    }
  } else if (EPI==2){
    unsigned char* Cl = (unsigned char*)&As[0][0][0];  // [256][64] fp8
    #pragma unroll
    for (int n=0;n<2;n++){
      int col = wn*32 + n*16 + fr;
      float bv = bias[n0 + col];
      #pragma unroll
      for (int m=0;m<4;m++){
        #pragma unroll
        for (int i=0;i<4;i++){
          int row = wm*64 + m*16 + fg*4 + i;
          float v = acc[m][n][i] + bv;
          // sigmoid-GELU: v * sigma(1.702 v), inf-safe form
          float e2 = __expf(-1.702f*v);
          float gg = v * __builtin_amdgcn_rcpf(1.f + e2);
          unsigned pk = (unsigned)__builtin_amdgcn_cvt_pk_fp8_f32(gg, gg, 0, false);
          Cl[row*64 + col] = (unsigned char)(pk & 0xff);
        }
      }
    }
    __syncthreads();
    const int rr = tid >> 2, slot = tid & 3;
    #pragma unroll
    for (int it=0; it<2; ++it){
      int row = it*128 + rr;
      short8 v = *(const short8*)&Cl[row*64 + slot*16];
      *(short8*)&((unsigned char*)outp)[(size_t)(m0+row)*N + n0 + slot*16] = v;
    }
  } else {
    float* Cl = (float*)&As[0][0][0];  // [256][64] fp32 (64 KB)
    #pragma unroll
    for (int n=0;n<2;n++){
      int col = wn*32 + n*16 + fr;
      float bv = bias[n0 + col];
      #pragma unroll
      for (int m=0;m<4;m++){
        #pragma unroll
        for (int i=0;i<4;i++){
          int row = wm*64 + m*16 + fg*4 + i;
          Cl[row*64 + col] = acc[m][n][i] + bv;
        }
      }
    }
    __syncthreads();
    const int rr = tid >> 4, slot = tid & 15;
    #pragma unroll
    for (int it=0; it<8; ++it){
      int row = it*32 + rr;
      float4 v = *(const float4*)&Cl[row*64 + slot*4];
      int p = tok2pix(m0+row);
      size_t idx = (size_t)p*CCH + n0 + slot*4;
      float4 rv = *(const float4*)&res[idx];
      v.x += rv.x; v.y += rv.y; v.z += rv.z; v.w += rv.w;
      *(float4*)&((float*)outp)[idx] = v;
    }
  }
}

// ---- fc2: fp8 x fp8 MFMA GEMM, BK=128 (half the barrier convoys of bf16).
// BM=256, BN=64, 8 waves (2M x 1N... wm=wid>>1, wn=wid&1 as bf16 version).
// 16B-granule XOR swizzle (write: pre-swizzled global src; read: ds_read_b64
// at p=(kk*2+(fg>>1))^(r&7)). out[t] = res[t] + A8[M,K]*B8[N,K]^T + bias.
template<int KK>
__global__ __launch_bounds__(512) void gemmF8(const unsigned char* __restrict__ A8,
    const unsigned char* __restrict__ B8, const float* __restrict__ bias,
    const float* __restrict__ res, float* __restrict__ outp,
    int N, int gx)
{
  __shared__ unsigned char As8[2][256][128];  // 64 KB
  __shared__ unsigned char Bs8[2][64][128];   // 16 KB
  const int tid = threadIdx.x, lane = tid & 63, wid = tid >> 6;
  const int fr = lane & 15, fg = lane >> 4;
  const int wm = wid >> 1, wn = wid & 1;

  const int nwg = gridDim.x;
  const int q = nwg >> 3, r = nwg & 7;
  const int xcd = blockIdx.x & 7, pos = blockIdx.x >> 3;
  const int wgid = (xcd < r ? xcd*(q+1) : r*(q+1) + (xcd-r)*q) + pos;
  const int m0 = (wgid / gx) * 256, n0 = (wgid % gx) * 64;

  floatx4 acc[4][2];
  #pragma unroll
  for (int m=0;m<4;m++)
    #pragma unroll
    for (int n=0;n<2;n++) acc[m][n] = (floatx4){0.f,0.f,0.f,0.f};

  const int srow = tid >> 3;
  const int scolb = ((tid & 7) ^ (srow & 7)) * 16;   // byte offset, 16B granule
  const unsigned char* gA = A8 + (size_t)(m0 + srow) * KK + scolb;
  const unsigned char* gB = B8 + (size_t)(n0 + srow) * KK + scolb;
  constexpr int a64 = 64 * KK;                        // byte stride of 64 rows
  unsigned char* aB = &As8[0][wid*8][0];
  unsigned char* bB = &Bs8[0][wid*8][0];
  constexpr int nt = KK >> 7;                         // BK=128 bytes

  const unsigned aLds = (unsigned)(uintptr_t)&As8[0][0][0];
  const unsigned bLds = (unsigned)(uintptr_t)&Bs8[0][0][0];
  const unsigned rowOffA = (unsigned)((wm*64 + fr)*128);
  const unsigned rowOffB = (unsigned)((wn*32 + fr)*128);
  unsigned pcc[4];
  #pragma unroll
  for (int kk=0;kk<4;kk++)
    pcc[kk] = (unsigned)((((kk*2 + (fg>>1)) ^ (fr&7))*16) + (fg&1)*8);

#define STAGE8(tt, bb) do{                                            \
    const int k0_ = (tt) << 7;                                        \
    unsigned char* a_ = aB + (bb)*256*128;                            \
    unsigned char* b_ = bB + (bb)*64*128;                             \
    gload16(gA + k0_,          a_);                                   \
    gload16(gA + k0_ +   a64,  a_ +  8192);                           \
    gload16(gA + k0_ + 2*a64,  a_ + 16384);                           \
    gload16(gA + k0_ + 3*a64,  a_ + 24576);                           \
    gload16(gB + k0_,          b_);                                   \
  }while(0)

  STAGE8(0, 0);
  #pragma unroll
  for (int t = 0; t < nt; ++t){
    const int buf = t & 1;
    if (t + 1 < nt){
      STAGE8(t+1, buf^1);
      waitvm<5>();
    } else {
      waitvm<0>();
    }
    __builtin_amdgcn_s_barrier();
    const unsigned aoff = aLds + (unsigned)buf*32768u + rowOffA;
    const unsigned boff = bLds + (unsigned)buf*8192u  + rowOffB;
    #pragma unroll
    for (int kk=0; kk<4; ++kk){
      const unsigned pc = pcc[kk];
      long af[4], bq[2];
      #pragma unroll
      for (int m=0;m<4;m++) af[m] = ds_read_b64s(aoff + (unsigned)(m*2048) + pc);
      #pragma unroll
      for (int n=0;n<2;n++) bq[n] = ds_read_b64s(boff + (unsigned)(n*2048) + pc);
      asm volatile("s_waitcnt lgkmcnt(0)" ::: "memory");
      __builtin_amdgcn_sched_barrier(0);
      __builtin_amdgcn_s_setprio(1);
      #pragma unroll
      for (int m=0;m<4;m++)
        #pragma unroll
        for (int n=0;n<2;n++)
          acc[m][n] = __builtin_amdgcn_mfma_f32_16x16x32_fp8_fp8(af[m], bq[n], acc[m][n], 0,0,0);
      __builtin_amdgcn_s_setprio(0);
    }
    __builtin_amdgcn_s_barrier();
  }
#undef STAGE8

  // ---- coalesced fp32 epilogue: out = res + v + bias ----
  __syncthreads();
  float* Cl = (float*)&As8[0][0][0];   // [256][64] fp32 (64 KB)
  #pragma unroll
  for (int n=0;n<2;n++){
    int col = wn*32 + n*16 + fr;
    float bv = bias[n0 + col];
    #pragma unroll
    for (int m=0;m<4;m++){
      #pragma unroll
      for (int i=0;i<4;i++){
        int row = wm*64 + m*16 + fg*4 + i;
        Cl[row*64 + col] = acc[m][n][i] + bv;
      }
    }
  }
  __syncthreads();
  const int rr = tid >> 4, slot = tid & 15;
  #pragma unroll
  for (int it=0; it<8; ++it){
    int row = it*32 + rr;
    float4 v = *(const float4*)&Cl[row*64 + slot*4];
    size_t idx = (size_t)(m0+row)*CCH + n0 + slot*4;
    float4 rv = *(const float4*)&res[idx];
    v.x += rv.x; v.y += rv.y; v.z += rv.z; v.w += rv.w;
    *(float4*)&outp[idx] = v;
  }
}

// ---- MFMA windowed attention: block = window, wave w -> heads w, w+4, w+8 ----
__global__ __launch_bounds__(256) void attn_mfma(const short* __restrict__ qkv,
    const float* __restrict__ rel_bias, short* __restrict__ attnout)
{
  __shared__ short Pl[4][64][68];
  __shared__ short Vt[4][32][68];
  __shared__ float lb[4][169];
  __shared__ int grp[64];
  const int wi = blockIdx.x;
  const int wid = threadIdx.x>>6, lane = threadIdx.x&63;
  const int fr = lane&15, fg = lane>>4;
  const int w = wi & 63, wh = w>>3, ww = w&7;
  if (threadIdx.x < 64){
    int t = threadIdx.x;
    int gv = 0;
    if (t < 49){
      int ai = t/7, aj = t%7;
      int hs = wh*7+ai, ws = ww*7+aj;
      int gh = hs<49?0:(hs<53?1:2);
      int gw = ws<49?0:(ws<53?1:2);
      gv = gh*3+gw;
    } else gv = -1;
    grp[t] = gv;
  }
  for (int t = lane; t < 32*15; t += 64){
    int d = t/15, j = 49 + t - d*15;
    Vt[wid][d][j] = 0;
  }
  __syncthreads();
  const size_t tbase = (size_t)wi*49;
  const float SCALE = 0.17677669529663687f;

  for (int hi=0; hi<3; ++hi){
    const int h = hi*4 + wid;
    for (int t = lane; t < 169; t += 64) lb[wid][t] = rel_bias[t*12 + h];
    for (int t = lane; t < 196; t += 64){
      int j = t>>2, d0 = (t&3)*8;
      short8 vv = *(const short8*)&qkv[(tbase+j)*1152 + 768 + h*32 + d0];
      #pragma unroll
      for (int s=0;s<8;s++) Vt[wid][d0+s][j] = vv[s];
    }
    short8 zf = {};
    short8 aq[4], bk[4];
    #pragma unroll
    for (int m=0;m<4;m++){
      int r = m*16+fr;
      aq[m] = (r<49) ? *(const short8*)&qkv[(tbase+r)*1152       + h*32 + fg*8] : zf;
      bk[m] = (r<49) ? *(const short8*)&qkv[(tbase+r)*1152 + 384 + h*32 + fg*8] : zf;
    }
    __syncthreads();   // (1) Vt/lb visible

    floatx4 sc[4][4];
    #pragma unroll
    for (int m=0;m<4;m++)
      #pragma unroll
      for (int n=0;n<4;n++)
        sc[m][n] = __builtin_amdgcn_mfma_f32_16x16x32_bf16(aq[m], bk[n], (floatx4){0.f,0.f,0.f,0.f}, 0,0,0);

    int ciC[4], cjC[4], gC[4], cvC[4];
    #pragma unroll
    for (int n=0;n<4;n++){
      int c = n*16+fr;
      ciC[n] = c/7; cjC[n] = c - ciC[n]*7;
      gC[n] = grp[c]; cvC[n] = (c<49);
    }
    #pragma unroll
    for (int m=0;m<4;m++){
      #pragma unroll
      for (int i=0;i<4;i++){
        int r = m*16 + fg*4 + i;
        int rv = (r<49);
        int ri = r/7, rj = r - ri*7;
        int gr = grp[r];
        float mxv = -3e30f;
        #pragma unroll
        for (int n=0;n<4;n++){
          float s;
          if (rv && cvC[n]){
            int dr = ri - ciC[n] + 6, dc = rj - cjC[n] + 6;
            s = sc[m][n][i]*SCALE + lb[wid][dr*13+dc];
            if (gr != gC[n]) s -= 100.f;
          } else s = -3e30f;
          sc[m][n][i] = s;
          mxv = fmaxf(mxv, s);
        }
        #pragma unroll
        for (int off=1;off<16;off<<=1) mxv = fmaxf(mxv, __shfl_xor(mxv, off));
        float sum = 0.f;
        #pragma unroll
        for (int n=0;n<4;n++){
          float e = __expf(sc[m][n][i]-mxv);
          sc[m][n][i] = e; sum += e;
        }
        #pragma unroll
        for (int off=1;off<16;off<<=1) sum += __shfl_xor(sum, off);
        float inv = 1.f/sum;
        #pragma unroll
        for (int n=0;n<4;n++)
          Pl[wid][r][n*16+fr] = f2bf(sc[m][n][i]*inv);
      }
    }
    __syncthreads();   // (2) P visible

    short8 pa[4][2], vb[2][2];
    #pragma unroll
    for (int m=0;m<4;m++)
      #pragma unroll
      for (int ks=0;ks<2;ks++)
        pa[m][ks] = *(const short8*)&Pl[wid][m*16+fr][ks*32+fg*8];
    #pragma unroll
    for (int n2=0;n2<2;n2++)
      #pragma unroll
      for (int ks=0;ks<2;ks++)
        vb[n2][ks] = *(const short8*)&Vt[wid][n2*16+fr][ks*32+fg*8];
    floatx4 oc[4][2];
    #pragma unroll
    for (int m=0;m<4;m++)
      #pragma unroll
      for (int n2=0;n2<2;n2++){
        oc[m][n2] = (floatx4){0.f,0.f,0.f,0.f};
        #pragma unroll
        for (int ks=0;ks<2;ks++)
          oc[m][n2] = __builtin_amdgcn_mfma_f32_16x16x32_bf16(pa[m][ks], vb[n2][ks], oc[m][n2], 0,0,0);
      }
    #pragma unroll
    for (int m=0;m<4;m++){
      #pragma unroll
      for (int i=0;i<4;i++){
        int r = m*16 + fg*4 + i;
        if (r < 49){
          #pragma unroll
          for (int n2=0;n2<2;n2++)
            attnout[(tbase+r)*384 + h*32 + n2*16 + fr] = f2bf(oc[m][n2][i]);
        }
      }
    }
    __syncthreads();   // (3) Vt reads done before next head's staging
  }
}

extern "C" void kernel_launch(void* const* d_in, const int* in_sizes, int n_in,
                              void* d_out, int out_size, void* d_ws, size_t ws_size,
                              hipStream_t stream)
{
  const float* x      = (const float*)d_in[0];
  const float* n1g    = (const float*)d_in[1];
  const float* n1b    = (const float*)d_in[2];
  const float* qkv_w  = (const float*)d_in[3];
  const float* qkv_b  = (const float*)d_in[4];
  const float* relb   = (const float*)d_in[5];
  const float* proj_w = (const float*)d_in[6];
  const float* proj_b = (const float*)d_in[7];
  const float* n2g    = (const float*)d_in[8];
  const float* n2b    = (const float*)d_in[9];
  const float* fc1_w  = (const float*)d_in[10];
  const float* fc1_b  = (const float*)d_in[11];
  const float* fc2_w  = (const float*)d_in[12];
  const float* fc2_b  = (const float*)d_in[13];

  char* ws = (char*)d_ws;
  const size_t SZ_XW  = (size_t)NTOK*CCH*2;
  const size_t SZ_QKV = (size_t)NTOK*1152*2;
  const size_t SZ_ATT = SZ_XW;
  const size_t SZ_Y   = (size_t)NTOK*CCH*4;

  short* xw    = (short*)(ws);
  short* qkvb  = (short*)(ws + SZ_XW);
  short* att   = (short*)(ws + SZ_XW + SZ_QKV);
  float* y     = (float*)(ws + SZ_XW + SZ_QKV + SZ_ATT);
  char*  wbuf  = ws + SZ_XW + SZ_QKV + SZ_ATT + SZ_Y;
  short* qkvWt = (short*)wbuf;                           // [1152][384] bf16
  short* projWt= qkvWt + (size_t)1152*384;               // [384][384] bf16
  short* fc1Wt = projWt + (size_t)384*384;               // [1536][384] bf16
  unsigned char* fc2Wt8 = (unsigned char*)(fc1Wt + (size_t)1536*384); // [384][1536] fp8
  unsigned char* hbuf8  = (unsigned char*)qkvb;          // [NTOK][1536] fp8 (reuses qkv)
  short* hin   = xw;                                     // [NTOK][384]  (reuses xw)

  wtconv<<<dim3((384*1152+255)/256), dim3(256), 0, stream>>>(qkv_w, qkvWt, 384, 1152);
  wtconv<<<dim3((384*384 +255)/256), dim3(256), 0, stream>>>(proj_w, projWt, 384, 384);
  wtconv<<<dim3((384*1536+255)/256), dim3(256), 0, stream>>>(fc1_w, fc1Wt, 384, 1536);
  wtconv8<<<dim3((1536*384+255)/256), dim3(256), 0, stream>>>(fc2_w, fc2Wt8, 1536, 384);

  ln_kernel<1><<<dim3(NTOK/4), dim3(256), 0, stream>>>(x, n1g, n1b, xw);
  gemm8<0,384><<<dim3(18*196), dim3(512), 0, stream>>>(xw,  qkvWt, qkv_b, nullptr, qkvb, 1152, 18);
  attn_mfma<<<dim3(NBATCH*NW), dim3(256), 0, stream>>>(qkvb, relb, att);
  gemm8<1,384><<<dim3(6*196),  dim3(512), 0, stream>>>(att, projWt, proj_b, x, y, 384, 6);
  ln_kernel<0><<<dim3(NTOK/4), dim3(256), 0, stream>>>(y, n2g, n2b, hin);
  gemm8<2,384><<<dim3(24*196), dim3(512), 0, stream>>>(hin, fc1Wt, fc1_b, nullptr, hbuf8, 1536, 24);
  gemmF8<1536><<<dim3(6*196),  dim3(512), 0, stream>>>(hbuf8, fc2Wt8, fc2_b, y, (float*)d_out, 384, 6);
}

// Round 14
// 350.904 us; speedup vs baseline: 2.5547x; 1.1439x over previous
//
#include <hip/hip_runtime.h>
#include <hip/hip_bf16.h>
#include <math.h>

#define NBATCH 16
#define NW 64
#define WA 49
#define NTOK (NBATCH*NW*WA)   // 50176
#define CCH 384
#define HIDDEN 1536

typedef __attribute__((ext_vector_type(8))) short short8;
typedef __attribute__((ext_vector_type(4))) float floatx4;

static __device__ __forceinline__ short f2bf(float f){
  unsigned u = __float_as_uint(f);
  unsigned r = (u + 0x7fff + ((u>>16)&1)) >> 16;
  return (short)r;
}
static __device__ __forceinline__ float bf2f(short s){
  return __uint_as_float(((unsigned)(unsigned short)s)<<16);
}

static __device__ __forceinline__ void gload16(const void* g, void* l){
  __builtin_amdgcn_global_load_lds(
      (const __attribute__((address_space(1))) void*)g,
      (__attribute__((address_space(3))) void*)l, 16, 0, 0);
}

// opaque LDS reads: compiler cannot see global_load_lds -> ds_read dependence;
// we own the waitcnts (rule #18: lgkmcnt + sched_barrier before MFMA).
static __device__ __forceinline__ short8 ds_read_b128s(unsigned addr){
  short8 r;
  asm volatile("ds_read_b128 %0, %1" : "=v"(r) : "v"(addr));
  return r;
}
static __device__ __forceinline__ long ds_read_b64s(unsigned addr){
  long r;
  asm volatile("ds_read_b64 %0, %1" : "=v"(r) : "v"(addr));
  return r;
}

template<int N> __device__ __forceinline__ void waitvm();
template<> __device__ __forceinline__ void waitvm<0>(){ asm volatile("s_waitcnt vmcnt(0)" ::: "memory"); }
template<> __device__ __forceinline__ void waitvm<5>(){ asm volatile("s_waitcnt vmcnt(5)" ::: "memory"); }

// token index -> pixel index (same map for LN1 gather and proj scatter)
static __device__ __forceinline__ int tok2pix(int t){
  int b = t / (NW*WA);
  int rem = t % (NW*WA);
  int w = rem / WA, a = rem % WA;
  int hs = (w>>3)*7 + a/7;
  int ws = (w&7)*7 + a%7;
  int hp = hs + 3; if (hp >= 56) hp -= 56;
  int wp = ws + 3; if (wp >= 56) wp -= 56;
  return (b*56 + hp)*56 + wp;
}

// ---- weight transpose + fp32->bf16 convert: W[K,N] -> Wt[N,K] ----
__global__ void wtconv(const float* __restrict__ W, short* __restrict__ Wt, int K, int N){
  int i = blockIdx.x*256 + threadIdx.x;
  if (i >= K*N) return;
  int k = i / N, n = i % N;
  Wt[(size_t)n*K + k] = f2bf(W[i]);
}

// ---- weight transpose + fp32->fp8(e4m3) convert: W[K,N] -> Wt8[N,K] ----
__global__ void wtconv8(const float* __restrict__ W, unsigned char* __restrict__ Wt, int K, int N){
  int i = blockIdx.x*256 + threadIdx.x;
  if (i >= K*N) return;
  int k = i / N, n = i % N;
  unsigned pk = (unsigned)__builtin_amdgcn_cvt_pk_fp8_f32(W[i], W[i], 0, false);
  Wt[(size_t)n*K + k] = (unsigned char)(pk & 0xff);
}

// ---- LayerNorm emitting fp8 e4m3 (one wave per token, lanes 0-47 active).
// MAP=1: gather via tok2pix (LN1+shift+window)
template<int MAP>
__global__ __launch_bounds__(256) void ln_fp8(const float* __restrict__ x,
    const float* __restrict__ g, const float* __restrict__ bta, unsigned char* __restrict__ out){
  int wid = threadIdx.x>>6, lane = threadIdx.x&63;
  int t = blockIdx.x*4 + wid;
  const float* row = x + (size_t)(MAP ? tok2pix(t) : t)*CCH;
  float v[8]; float s=0.f, ss=0.f;
  if (lane < 48){
    float4 p0 = *(const float4*)&row[lane*8];
    float4 p1 = *(const float4*)&row[lane*8+4];
    v[0]=p0.x;v[1]=p0.y;v[2]=p0.z;v[3]=p0.w;
    v[4]=p1.x;v[5]=p1.y;v[6]=p1.z;v[7]=p1.w;
    #pragma unroll
    for (int i=0;i<8;i++){ s+=v[i]; ss+=v[i]*v[i]; }
  }
  #pragma unroll
  for (int off=32; off; off>>=1){ s += __shfl_xor(s,off); ss += __shfl_xor(ss,off); }
  float mean = s*(1.f/384.f);
  float var  = ss*(1.f/384.f) - mean*mean;
  float inv  = rsqrtf(var + 1e-5f);
  if (lane < 48){
    float4 g0 = *(const float4*)&g[lane*8],  g1 = *(const float4*)&g[lane*8+4];
    float4 b0 = *(const float4*)&bta[lane*8],b1 = *(const float4*)&bta[lane*8+4];
    float o[8];
    o[0]=(v[0]-mean)*inv*g0.x+b0.x; o[1]=(v[1]-mean)*inv*g0.y+b0.y;
    o[2]=(v[2]-mean)*inv*g0.z+b0.z; o[3]=(v[3]-mean)*inv*g0.w+b0.w;
    o[4]=(v[4]-mean)*inv*g1.x+b1.x; o[5]=(v[5]-mean)*inv*g1.y+b1.y;
    o[6]=(v[6]-mean)*inv*g1.z+b1.z; o[7]=(v[7]-mean)*inv*g1.w+b1.w;
    unsigned w0 = (unsigned)__builtin_amdgcn_cvt_pk_fp8_f32(o[0], o[1], 0, false);
    w0 = (unsigned)__builtin_amdgcn_cvt_pk_fp8_f32(o[2], o[3], (int)w0, true);
    unsigned w1 = (unsigned)__builtin_amdgcn_cvt_pk_fp8_f32(o[4], o[5], 0, false);
    w1 = (unsigned)__builtin_amdgcn_cvt_pk_fp8_f32(o[6], o[7], (int)w1, true);
    uint2 pk; pk.x = w0; pk.y = w1;
    *(uint2*)&out[(size_t)t*CCH + lane*8] = pk;
  }
}

// ---- 8-wave pipelined bf16 MFMA GEMM (proj only) w/ coalesced epilogue.
// BM=256, BN=64, BK=64, double-buffered, counted vmcnt(5), XOR-swizzled LDS.
// EPI 1: proj -> y[pix] = x[pix] + v
template<int EPI, int KK>
__global__ __launch_bounds__(512) void gemm8(const short* __restrict__ A,
    const short* __restrict__ Bt, const float* __restrict__ bias,
    const float* __restrict__ res, void* __restrict__ outp,
    int N, int gx)
{
  __shared__ short As[2][256][64];   // 64 KB (reused as C-tile in epilogue)
  __shared__ short Bs[2][64][64];    // 16 KB
  const int tid = threadIdx.x, lane = tid & 63, wid = tid >> 6;
  const int fr = lane & 15, fg = lane >> 4;
  const int wm = wid >> 1, wn = wid & 1;

  const int nwg = gridDim.x;
  const int q = nwg >> 3, r = nwg & 7;
  const int xcd = blockIdx.x & 7, pos = blockIdx.x >> 3;
  const int wgid = (xcd < r ? xcd*(q+1) : r*(q+1) + (xcd-r)*q) + pos;
  const int m0 = (wgid / gx) * 256, n0 = (wgid % gx) * 64;

  floatx4 acc[4][2];
  #pragma unroll
  for (int m=0;m<4;m++)
    #pragma unroll
    for (int n=0;n<2;n++) acc[m][n] = (floatx4){0.f,0.f,0.f,0.f};

  const int srow = tid >> 3;
  const int scol = ((tid & 7) ^ (srow & 7)) * 8;
  const short* gA = A  + (size_t)(m0 + srow) * KK + scol;
  const short* gB = Bt + (size_t)(n0 + srow) * KK + scol;
  constexpr int a64 = 64 * KK;
  short* aB = &As[0][wid*8][0];
  short* bB = &Bs[0][wid*8][0];
  constexpr int nt = KK >> 6;

  const unsigned aLds = (unsigned)(uintptr_t)&As[0][0][0];
  const unsigned bLds = (unsigned)(uintptr_t)&Bs[0][0][0];
  const unsigned rowOffA = (unsigned)((wm*64 + fr)*128);
  const unsigned rowOffB = (unsigned)((wn*32 + fr)*128);
  const unsigned pc0 = (unsigned)(((fg  ) ^ (fr&7))*16);
  const unsigned pc1 = (unsigned)(((4+fg) ^ (fr&7))*16);

#define STAGE(tt, bb) do{                                             \
    const int k0_ = (tt) << 6;                                        \
    short* a_ = aB + (bb)*256*64;                                     \
    short* b_ = bB + (bb)*64*64;                                      \
    gload16(gA + k0_,          a_);                                   \
    gload16(gA + k0_ +   a64,  a_ +  64*64);                          \
    gload16(gA + k0_ + 2*a64,  a_ + 128*64);                          \
    gload16(gA + k0_ + 3*a64,  a_ + 192*64);                          \
    gload16(gB + k0_,          b_);                                   \
  }while(0)

  STAGE(0, 0);
  #pragma unroll
  for (int t = 0; t < nt; ++t){
    const int buf = t & 1;
    if (t + 1 < nt){
      STAGE(t+1, buf^1);
      waitvm<5>();
    } else {
      waitvm<0>();
    }
    __builtin_amdgcn_s_barrier();
    const unsigned aoff = aLds + (unsigned)buf*32768u + rowOffA;
    const unsigned boff = bLds + (unsigned)buf*8192u  + rowOffB;
    #pragma unroll
    for (int kk=0; kk<2; ++kk){
      const unsigned pc = kk ? pc1 : pc0;
      short8 af[4], bq[2];
      #pragma unroll
      for (int m=0;m<4;m++) af[m] = ds_read_b128s(aoff + (unsigned)(m*2048) + pc);
      #pragma unroll
      for (int n=0;n<2;n++) bq[n] = ds_read_b128s(boff + (unsigned)(n*2048) + pc);
      asm volatile("s_waitcnt lgkmcnt(0)" ::: "memory");
      __builtin_amdgcn_sched_barrier(0);
      __builtin_amdgcn_s_setprio(1);
      #pragma unroll
      for (int m=0;m<4;m++)
        #pragma unroll
        for (int n=0;n<2;n++)
          acc[m][n] = __builtin_amdgcn_mfma_f32_16x16x32_bf16(af[m], bq[n], acc[m][n], 0,0,0);
      __builtin_amdgcn_s_setprio(0);
    }
    __builtin_amdgcn_s_barrier();
  }
#undef STAGE

  // ---- LDS-staged coalesced fp32 epilogue (proj): y[pix] = x[pix] + v ----
  __syncthreads();
  float* Cl = (float*)&As[0][0][0];  // [256][64] fp32 (64 KB)
  #pragma unroll
  for (int n=0;n<2;n++){
    int col = wn*32 + n*16 + fr;
    float bv = bias[n0 + col];
    #pragma unroll
    for (int m=0;m<4;m++){
      #pragma unroll
      for (int i=0;i<4;i++){
        int row = wm*64 + m*16 + fg*4 + i;
        Cl[row*64 + col] = acc[m][n][i] + bv;
      }
    }
  }
  __syncthreads();
  const int rr = tid >> 4, slot = tid & 15;
  #pragma unroll
  for (int it=0; it<8; ++it){
    int row = it*32 + rr;
    float4 v = *(const float4*)&Cl[row*64 + slot*4];
    int p = tok2pix(m0+row);
    size_t idx = (size_t)p*CCH + n0 + slot*4;
    float4 rv = *(const float4*)&res[idx];
    v.x += rv.x; v.y += rv.y; v.z += rv.z; v.w += rv.w;
    *(float4*)&((float*)outp)[idx] = v;
  }
}

// ---- fp8 x fp8 MFMA GEMM, BK=128 bytes (half the convoys of bf16 BK=64).
// BM=256, BN=64, 8 waves (2M x 1N per wave pair). 16B-granule XOR swizzle.
// EPI 0: store bf16 (qkv)   EPI 2: sigmoid-GELU -> fp8 (fc1)
// EPI 3: out[t] = res[t] + v + bias (fc2, fp32)
template<int EPI, int KK>
__global__ __launch_bounds__(512) void gemmF8(const unsigned char* __restrict__ A8,
    const unsigned char* __restrict__ B8, const float* __restrict__ bias,
    const float* __restrict__ res, void* __restrict__ outp,
    int N, int gx)
{
  __shared__ unsigned char As8[2][256][128];  // 64 KB (reused as C-tile)
  __shared__ unsigned char Bs8[2][64][128];   // 16 KB
  const int tid = threadIdx.x, lane = tid & 63, wid = tid >> 6;
  const int fr = lane & 15, fg = lane >> 4;
  const int wm = wid >> 1, wn = wid & 1;

  const int nwg = gridDim.x;
  const int q = nwg >> 3, r = nwg & 7;
  const int xcd = blockIdx.x & 7, pos = blockIdx.x >> 3;
  const int wgid = (xcd < r ? xcd*(q+1) : r*(q+1) + (xcd-r)*q) + pos;
  const int m0 = (wgid / gx) * 256, n0 = (wgid % gx) * 64;

  floatx4 acc[4][2];
  #pragma unroll
  for (int m=0;m<4;m++)
    #pragma unroll
    for (int n=0;n<2;n++) acc[m][n] = (floatx4){0.f,0.f,0.f,0.f};

  const int srow = tid >> 3;
  const int scolb = ((tid & 7) ^ (srow & 7)) * 16;   // byte offset, 16B granule
  const unsigned char* gA = A8 + (size_t)(m0 + srow) * KK + scolb;
  const unsigned char* gB = B8 + (size_t)(n0 + srow) * KK + scolb;
  constexpr int a64 = 64 * KK;                        // byte stride of 64 rows
  unsigned char* aB = &As8[0][wid*8][0];
  unsigned char* bB = &Bs8[0][wid*8][0];
  constexpr int nt = KK >> 7;                         // BK=128 bytes

  const unsigned aLds = (unsigned)(uintptr_t)&As8[0][0][0];
  const unsigned bLds = (unsigned)(uintptr_t)&Bs8[0][0][0];
  const unsigned rowOffA = (unsigned)((wm*64 + fr)*128);
  const unsigned rowOffB = (unsigned)((wn*32 + fr)*128);
  unsigned pcc[4];
  #pragma unroll
  for (int kk=0;kk<4;kk++)
    pcc[kk] = (unsigned)((((kk*2 + (fg>>1)) ^ (fr&7))*16) + (fg&1)*8);

#define STAGE8(tt, bb) do{                                            \
    const int k0_ = (tt) << 7;                                        \
    unsigned char* a_ = aB + (bb)*256*128;                            \
    unsigned char* b_ = bB + (bb)*64*128;                             \
    gload16(gA + k0_,          a_);                                   \
    gload16(gA + k0_ +   a64,  a_ +  8192);                           \
    gload16(gA + k0_ + 2*a64,  a_ + 16384);                           \
    gload16(gA + k0_ + 3*a64,  a_ + 24576);                           \
    gload16(gB + k0_,          b_);                                   \
  }while(0)

  STAGE8(0, 0);
  #pragma unroll
  for (int t = 0; t < nt; ++t){
    const int buf = t & 1;
    if (t + 1 < nt){
      STAGE8(t+1, buf^1);
      waitvm<5>();
    } else {
      waitvm<0>();
    }
    __builtin_amdgcn_s_barrier();
    const unsigned aoff = aLds + (unsigned)buf*32768u + rowOffA;
    const unsigned boff = bLds + (unsigned)buf*8192u  + rowOffB;
    #pragma unroll
    for (int kk=0; kk<4; ++kk){
      const unsigned pc = pcc[kk];
      long af[4], bq[2];
      #pragma unroll
      for (int m=0;m<4;m++) af[m] = ds_read_b64s(aoff + (unsigned)(m*2048) + pc);
      #pragma unroll
      for (int n=0;n<2;n++) bq[n] = ds_read_b64s(boff + (unsigned)(n*2048) + pc);
      asm volatile("s_waitcnt lgkmcnt(0)" ::: "memory");
      __builtin_amdgcn_sched_barrier(0);
      __builtin_amdgcn_s_setprio(1);
      #pragma unroll
      for (int m=0;m<4;m++)
        #pragma unroll
        for (int n=0;n<2;n++)
          acc[m][n] = __builtin_amdgcn_mfma_f32_16x16x32_fp8_fp8(af[m], bq[n], acc[m][n], 0,0,0);
      __builtin_amdgcn_s_setprio(0);
    }
    __builtin_amdgcn_s_barrier();
  }
#undef STAGE8

  // ---- LDS-staged coalesced epilogue ----
  __syncthreads();
  if (EPI==0){
    short* Cl = (short*)&As8[0][0][0];  // [256][64] bf16 (32 KB)
    #pragma unroll
    for (int n=0;n<2;n++){
      int col = wn*32 + n*16 + fr;
      float bv = bias[n0 + col];
      #pragma unroll
      for (int m=0;m<4;m++){
        #pragma unroll
        for (int i=0;i<4;i++){
          int row = wm*64 + m*16 + fg*4 + i;
          Cl[row*64 + col] = f2bf(acc[m][n][i] + bv);
        }
      }
    }
    __syncthreads();
    const int rr = tid >> 3, slot = tid & 7;
    #pragma unroll
    for (int it=0; it<4; ++it){
      int row = it*64 + rr;
      short8 v = *(const short8*)&Cl[row*64 + slot*8];
      *(short8*)&((short*)outp)[(size_t)(m0+row)*N + n0 + slot*8] = v;
    }
  } else if (EPI==2){
    unsigned char* Cl = (unsigned char*)&As8[0][0][0];  // [256][64] fp8
    #pragma unroll
    for (int n=0;n<2;n++){
      int col = wn*32 + n*16 + fr;
      float bv = bias[n0 + col];
      #pragma unroll
      for (int m=0;m<4;m++){
        #pragma unroll
        for (int i=0;i<4;i++){
          int row = wm*64 + m*16 + fg*4 + i;
          float v = acc[m][n][i] + bv;
          // sigmoid-GELU: v * sigma(1.702 v), inf-safe form
          float e2 = __expf(-1.702f*v);
          float gg = v * __builtin_amdgcn_rcpf(1.f + e2);
          unsigned pk = (unsigned)__builtin_amdgcn_cvt_pk_fp8_f32(gg, gg, 0, false);
          Cl[row*64 + col] = (unsigned char)(pk & 0xff);
        }
      }
    }
    __syncthreads();
    const int rr = tid >> 2, slot = tid & 3;
    #pragma unroll
    for (int it=0; it<2; ++it){
      int row = it*128 + rr;
      short8 v = *(const short8*)&Cl[row*64 + slot*16];
      *(short8*)&((unsigned char*)outp)[(size_t)(m0+row)*N + n0 + slot*16] = v;
    }
  } else {
    float* Cl = (float*)&As8[0][0][0];   // [256][64] fp32 (64 KB)
    #pragma unroll
    for (int n=0;n<2;n++){
      int col = wn*32 + n*16 + fr;
      float bv = bias[n0 + col];
      #pragma unroll
      for (int m=0;m<4;m++){
        #pragma unroll
        for (int i=0;i<4;i++){
          int row = wm*64 + m*16 + fg*4 + i;
          Cl[row*64 + col] = acc[m][n][i] + bv;
        }
      }
    }
    __syncthreads();
    const int rr = tid >> 4, slot = tid & 15;
    #pragma unroll
    for (int it=0; it<8; ++it){
      int row = it*32 + rr;
      float4 v = *(const float4*)&Cl[row*64 + slot*4];
      size_t idx = (size_t)(m0+row)*CCH + n0 + slot*4;
      float4 rv = *(const float4*)&res[idx];
      v.x += rv.x; v.y += rv.y; v.z += rv.z; v.w += rv.w;
      *(float4*)&((float*)outp)[idx] = v;
    }
  }
}

// ---- MFMA windowed attention: block = window, wave w -> heads w, w+4, w+8 ----
__global__ __launch_bounds__(256) void attn_mfma(const short* __restrict__ qkv,
    const float* __restrict__ rel_bias, short* __restrict__ attnout)
{
  __shared__ short Pl[4][64][68];
  __shared__ short Vt[4][32][68];
  __shared__ float lb[4][169];
  __shared__ int grp[64];
  const int wi = blockIdx.x;
  const int wid = threadIdx.x>>6, lane = threadIdx.x&63;
  const int fr = lane&15, fg = lane>>4;
  const int w = wi & 63, wh = w>>3, ww = w&7;
  if (threadIdx.x < 64){
    int t = threadIdx.x;
    int gv = 0;
    if (t < 49){
      int ai = t/7, aj = t%7;
      int hs = wh*7+ai, ws = ww*7+aj;
      int gh = hs<49?0:(hs<53?1:2);
      int gw = ws<49?0:(ws<53?1:2);
      gv = gh*3+gw;
    } else gv = -1;
    grp[t] = gv;
  }
  for (int t = lane; t < 32*15; t += 64){
    int d = t/15, j = 49 + t - d*15;
    Vt[wid][d][j] = 0;
  }
  __syncthreads();
  const size_t tbase = (size_t)wi*49;
  const float SCALE = 0.17677669529663687f;

  for (int hi=0; hi<3; ++hi){
    const int h = hi*4 + wid;
    for (int t = lane; t < 169; t += 64) lb[wid][t] = rel_bias[t*12 + h];
    for (int t = lane; t < 196; t += 64){
      int j = t>>2, d0 = (t&3)*8;
      short8 vv = *(const short8*)&qkv[(tbase+j)*1152 + 768 + h*32 + d0];
      #pragma unroll
      for (int s=0;s<8;s++) Vt[wid][d0+s][j] = vv[s];
    }
    short8 zf = {};
    short8 aq[4], bk[4];
    #pragma unroll
    for (int m=0;m<4;m++){
      int r = m*16+fr;
      aq[m] = (r<49) ? *(const short8*)&qkv[(tbase+r)*1152       + h*32 + fg*8] : zf;
      bk[m] = (r<49) ? *(const short8*)&qkv[(tbase+r)*1152 + 384 + h*32 + fg*8] : zf;
    }
    __syncthreads();   // (1) Vt/lb visible

    floatx4 sc[4][4];
    #pragma unroll
    for (int m=0;m<4;m++)
      #pragma unroll
      for (int n=0;n<4;n++)
        sc[m][n] = __builtin_amdgcn_mfma_f32_16x16x32_bf16(aq[m], bk[n], (floatx4){0.f,0.f,0.f,0.f}, 0,0,0);

    int ciC[4], cjC[4], gC[4], cvC[4];
    #pragma unroll
    for (int n=0;n<4;n++){
      int c = n*16+fr;
      ciC[n] = c/7; cjC[n] = c - ciC[n]*7;
      gC[n] = grp[c]; cvC[n] = (c<49);
    }
    #pragma unroll
    for (int m=0;m<4;m++){
      #pragma unroll
      for (int i=0;i<4;i++){
        int r = m*16 + fg*4 + i;
        int rv = (r<49);
        int ri = r/7, rj = r - ri*7;
        int gr = grp[r];
        float mxv = -3e30f;
        #pragma unroll
        for (int n=0;n<4;n++){
          float s;
          if (rv && cvC[n]){
            int dr = ri - ciC[n] + 6, dc = rj - cjC[n] + 6;
            s = sc[m][n][i]*SCALE + lb[wid][dr*13+dc];
            if (gr != gC[n]) s -= 100.f;
          } else s = -3e30f;
          sc[m][n][i] = s;
          mxv = fmaxf(mxv, s);
        }
        #pragma unroll
        for (int off=1;off<16;off<<=1) mxv = fmaxf(mxv, __shfl_xor(mxv, off));
        float sum = 0.f;
        #pragma unroll
        for (int n=0;n<4;n++){
          float e = __expf(sc[m][n][i]-mxv);
          sc[m][n][i] = e; sum += e;
        }
        #pragma unroll
        for (int off=1;off<16;off<<=1) sum += __shfl_xor(sum, off);
        float inv = 1.f/sum;
        #pragma unroll
        for (int n=0;n<4;n++)
          Pl[wid][r][n*16+fr] = f2bf(sc[m][n][i]*inv);
      }
    }
    __syncthreads();   // (2) P visible

    short8 pa[4][2], vb[2][2];
    #pragma unroll
    for (int m=0;m<4;m++)
      #pragma unroll
      for (int ks=0;ks<2;ks++)
        pa[m][ks] = *(const short8*)&Pl[wid][m*16+fr][ks*32+fg*8];
    #pragma unroll
    for (int n2=0;n2<2;n2++)
      #pragma unroll
      for (int ks=0;ks<2;ks++)
        vb[n2][ks] = *(const short8*)&Vt[wid][n2*16+fr][ks*32+fg*8];
    floatx4 oc[4][2];
    #pragma unroll
    for (int m=0;m<4;m++)
      #pragma unroll
      for (int n2=0;n2<2;n2++){
        oc[m][n2] = (floatx4){0.f,0.f,0.f,0.f};
        #pragma unroll
        for (int ks=0;ks<2;ks++)
          oc[m][n2] = __builtin_amdgcn_mfma_f32_16x16x32_bf16(pa[m][ks], vb[n2][ks], oc[m][n2], 0,0,0);
      }
    #pragma unroll
    for (int m=0;m<4;m++){
      #pragma unroll
      for (int i=0;i<4;i++){
        int r = m*16 + fg*4 + i;
        if (r < 49){
          #pragma unroll
          for (int n2=0;n2<2;n2++)
            attnout[(tbase+r)*384 + h*32 + n2*16 + fr] = f2bf(oc[m][n2][i]);
        }
      }
    }
    __syncthreads();   // (3) Vt reads done before next head's staging
  }
}

extern "C" void kernel_launch(void* const* d_in, const int* in_sizes, int n_in,
                              void* d_out, int out_size, void* d_ws, size_t ws_size,
                              hipStream_t stream)
{
  const float* x      = (const float*)d_in[0];
  const float* n1g    = (const float*)d_in[1];
  const float* n1b    = (const float*)d_in[2];
  const float* qkv_w  = (const float*)d_in[3];
  const float* qkv_b  = (const float*)d_in[4];
  const float* relb   = (const float*)d_in[5];
  const float* proj_w = (const float*)d_in[6];
  const float* proj_b = (const float*)d_in[7];
  const float* n2g    = (const float*)d_in[8];
  const float* n2b    = (const float*)d_in[9];
  const float* fc1_w  = (const float*)d_in[10];
  const float* fc1_b  = (const float*)d_in[11];
  const float* fc2_w  = (const float*)d_in[12];
  const float* fc2_b  = (const float*)d_in[13];

  char* ws = (char*)d_ws;
  const size_t SZ_XW  = (size_t)NTOK*CCH*2;
  const size_t SZ_QKV = (size_t)NTOK*1152*2;
  const size_t SZ_ATT = SZ_XW;
  const size_t SZ_Y   = (size_t)NTOK*CCH*4;

  unsigned char* xw8 = (unsigned char*)(ws);             // [NTOK][384] fp8
  short* qkvb  = (short*)(ws + SZ_XW);                   // [NTOK][1152] bf16
  short* att   = (short*)(ws + SZ_XW + SZ_QKV);          // [NTOK][384] bf16
  float* y     = (float*)(ws + SZ_XW + SZ_QKV + SZ_ATT); // [NTOK][384] fp32
  char*  wbuf  = ws + SZ_XW + SZ_QKV + SZ_ATT + SZ_Y;
  unsigned char* qkvW8 = (unsigned char*)wbuf;                     // [1152][384] fp8
  short* projWt        = (short*)(qkvW8 + (size_t)1152*384);       // [384][384] bf16
  unsigned char* fc1W8 = (unsigned char*)(projWt + (size_t)384*384); // [1536][384] fp8
  unsigned char* fc2W8 = fc1W8 + (size_t)1536*384;                 // [384][1536] fp8
  unsigned char* hbuf8 = (unsigned char*)qkvb;           // [NTOK][1536] fp8 (reuses qkv)
  unsigned char* hin8  = xw8;                            // [NTOK][384] fp8 (reuses xw)

  wtconv8<<<dim3((384*1152+255)/256), dim3(256), 0, stream>>>(qkv_w, qkvW8, 384, 1152);
  wtconv<<<dim3((384*384 +255)/256), dim3(256), 0, stream>>>(proj_w, projWt, 384, 384);
  wtconv8<<<dim3((384*1536+255)/256), dim3(256), 0, stream>>>(fc1_w, fc1W8, 384, 1536);
  wtconv8<<<dim3((1536*384+255)/256), dim3(256), 0, stream>>>(fc2_w, fc2W8, 1536, 384);

  ln_fp8<1><<<dim3(NTOK/4), dim3(256), 0, stream>>>(x, n1g, n1b, xw8);
  gemmF8<0,384><<<dim3(18*196), dim3(512), 0, stream>>>(xw8, qkvW8, qkv_b, nullptr, qkvb, 1152, 18);
  attn_mfma<<<dim3(NBATCH*NW), dim3(256), 0, stream>>>(qkvb, relb, att);
  gemm8<1,384><<<dim3(6*196),  dim3(512), 0, stream>>>(att, projWt, proj_b, x, y, 384, 6);
  ln_fp8<0><<<dim3(NTOK/4), dim3(256), 0, stream>>>(y, n2g, n2b, hin8);
  gemmF8<2,384><<<dim3(24*196), dim3(512), 0, stream>>>(hin8, fc1W8, fc1_b, nullptr, hbuf8, 1536, 24);
  gemmF8<3,1536><<<dim3(6*196), dim3(512), 0, stream>>>(hbuf8, fc2W8, fc2_b, y, (float*)d_out, 384, 6);
}